// Round 10
// baseline (254.520 us; speedup 1.0000x reference)
//
#include <hip/hip_runtime.h>
#include <hip/hip_bf16.h>
#include <hip/hip_fp16.h>
#include <math.h>

// Problem constants
#define B_ 2
#define S_ 2048
#define H_ 1024
#define A_ 1024
#define NH_ 16
#define HD_ 64
#define H3_ 3072
#define EPS_ 1e-5f

typedef __attribute__((ext_vector_type(8))) short short8;   // 8 bf16 in 4 VGPRs
typedef __attribute__((ext_vector_type(4))) float floatx4;  // MFMA accumulator
typedef __attribute__((ext_vector_type(4))) _Float16 half4v; // 4 f16 in 2 VGPRs
typedef __attribute__((ext_vector_type(2))) __fp16 fp16x2;   // cvt_pkrtz result type

__device__ inline unsigned short f2bf(float x) {
    union { float f; unsigned u; } v; v.f = x;
    unsigned r = v.u + 0x7fffu + ((v.u >> 16) & 1u);   // RNE
    return (unsigned short)(r >> 16);
}

// packed f32x2 -> bf16x2 (v_cvt_pk_bf16_f32 on gfx950)
__device__ inline unsigned pk_bf16(float a, float b) {
    union { __hip_bfloat162 h; unsigned u; } v;
    v.h = __float22bfloat162_rn(make_float2(a, b));
    return v.u;
}

// packed f32x2 -> f16x2 (RNE)
__device__ inline unsigned pk_f16(float a, float b) {
    union { __half2 h; unsigned u; } v;
    v.h = __float22half2_rn(make_float2(a, b));
    return v.u;
}

// async global->LDS, 16B per lane; LDS dst must be wave-uniform base + lane*16
__device__ inline void gld_lds16(const void* g, void* l) {
    __builtin_amdgcn_global_load_lds(
        (const __attribute__((address_space(1))) unsigned int*)g,
        (__attribute__((address_space(3))) unsigned int*)l, 16, 0, 0);
}

// GEMM barriers: BARE s_barrier, no sched_barrier pinning (m141: order-pinning
// regresses −42%; the compiler's own interleave is near-optimal). The inline
// waitcnts keep their "memory" clobber = compiler-level fence for memory ops.
#define BARE_BARRIER() __builtin_amdgcn_s_barrier()

// attn barrier (R9-verified winner): sched-fenced raw barrier — unchanged.
#define SFENCE() __builtin_amdgcn_sched_barrier(0)
#define RAW_BARRIER() do { SFENCE(); __builtin_amdgcn_s_barrier(); SFENCE(); } while (0)

// ---------------------------------------------------------------------------
// Kernel 0: fp32 -> bf16 cast (weights), 8 elems/thread
// ---------------------------------------------------------------------------
__global__ __launch_bounds__(256) void cast_bf16_kernel(
    const float* __restrict__ in, unsigned short* __restrict__ out, int n)
{
    int i = (blockIdx.x * 256 + threadIdx.x) * 8;
    if (i >= n) return;
    float4 a = *(const float4*)(in + i);
    float4 b = *(const float4*)(in + i + 4);
    uint4 o;
    o.x = pk_bf16(a.x, a.y);
    o.y = pk_bf16(a.z, a.w);
    o.z = pk_bf16(b.x, b.y);
    o.w = pk_bf16(b.z, b.w);
    *(uint4*)(out + i) = o;
}

// ---------------------------------------------------------------------------
// Kernel 1: mod = silu(ada_cond) @ mod_w^T + mod_b     [B, 3H]
// ---------------------------------------------------------------------------
__global__ __launch_bounds__(256) void mod_gemv_kernel(
    const float* __restrict__ ada, const float* __restrict__ mod_w,
    const float* __restrict__ mod_b, float* __restrict__ mod)
{
    int wid = threadIdx.x >> 6;
    int lane = threadIdx.x & 63;
    int idx = blockIdx.x * 4 + wid;       // 0 .. B*3H-1
    int b = idx / H3_;
    int j = idx % H3_;
    const float* ar = ada + (size_t)b * A_;
    const float* wr = mod_w + (size_t)j * A_;
    float acc = 0.f;
    for (int a = lane; a < A_; a += 64) {
        float av = ar[a];
        float sv = av / (1.f + __expf(-av));   // silu
        acc += sv * wr[a];
    }
    #pragma unroll
    for (int m = 1; m < 64; m <<= 1) acc += __shfl_xor(acc, m);
    if (lane == 0) mod[idx] = acc + mod_b[j];
}

// ---------------------------------------------------------------------------
// Kernel 2: h = layernorm(x)*ln_w * (scale+1) + shift -> bf16  [B,S,H]
// ---------------------------------------------------------------------------
__global__ __launch_bounds__(256) void ln_mod_kernel(
    const float* __restrict__ x, const float* __restrict__ ln_w,
    const float* __restrict__ mod, unsigned short* __restrict__ hout)
{
    int row = blockIdx.x;          // over B*S
    int b = row >> 11;             // row / 2048
    const float* xr = x + (size_t)row * H_;
    int t = threadIdx.x;
    float4 xv = *(const float4*)(xr + t * 4);
    float s1 = xv.x + xv.y + xv.z + xv.w;
    float s2 = xv.x*xv.x + xv.y*xv.y + xv.z*xv.z + xv.w*xv.w;
    #pragma unroll
    for (int m = 1; m < 64; m <<= 1) { s1 += __shfl_xor(s1, m); s2 += __shfl_xor(s2, m); }
    __shared__ float r1[4], r2[4];
    int wid = t >> 6, lane = t & 63;
    if (lane == 0) { r1[wid] = s1; r2[wid] = s2; }
    __syncthreads();
    s1 = r1[0] + r1[1] + r1[2] + r1[3];
    s2 = r2[0] + r2[1] + r2[2] + r2[3];
    float mean = s1 * (1.f / H_);
    float var  = s2 * (1.f / H_) - mean * mean;
    float rstd = rsqrtf(var + EPS_);
    const float* mrow = mod + (size_t)b * H3_;
    float4 wv = *(const float4*)(ln_w + t * 4);
    float4 sc = *(const float4*)(mrow + t * 4);
    float4 sh = *(const float4*)(mrow + H_ + t * 4);
    float4 hv;
    hv.x = (xv.x - mean) * rstd * wv.x * (sc.x + 1.f) + sh.x;
    hv.y = (xv.y - mean) * rstd * wv.y * (sc.y + 1.f) + sh.y;
    hv.z = (xv.z - mean) * rstd * wv.z * (sc.z + 1.f) + sh.z;
    hv.w = (xv.w - mean) * rstd * wv.w * (sc.w + 1.f) + sh.w;
    uint2 o;
    o.x = pk_bf16(hv.x, hv.y);
    o.y = pk_bf16(hv.z, hv.w);
    *(uint2*)(hout + (size_t)row * H_ + t * 4) = o;
}

// ---------------------------------------------------------------------------
// Kernel 3: QKV GEMM with FUSED qk-LN + RoPE epilogue.
// Round-17: T4 counted-vmcnt 3-buffer pipeline (R9 structure, verified
// correct) WITHOUT sched_barrier pinning — bare s_barrier lets the compiler
// interleave ds_read/MFMA/stage freely (m141 lesson).
// ---------------------------------------------------------------------------
__global__ __launch_bounds__(256) void gemm_qkv_fused_kernel(
    const unsigned short* __restrict__ A, const unsigned short* __restrict__ Bm,
    const float* __restrict__ freqs, const float* __restrict__ qn_w,
    const float* __restrict__ kn_w, unsigned short* __restrict__ qout,
    unsigned short* __restrict__ kout, unsigned short* __restrict__ vtout)
{
    __shared__ unsigned short As[3][128 * 32];
    __shared__ unsigned short Bs[3][128 * 32];
    const int K = H_;
    const int NIT = K / 32;               // 32
    int t = threadIdx.x;
    int w = t >> 6, lane = t & 63;
    int q16 = lane & 15, quad = lane >> 4;
    int wm = w >> 1, wn = w & 1;
    int m0 = blockIdx.y * 128, n0 = blockIdx.x * 128;

    // staging source (pre-swizzled): instr j covers rows w*32+j*16 .. +15
    int srow = 2 * (lane >> 3) + ((lane >> 2) & 1);
    int scol = ((lane & 3) ^ ((lane >> 3) & 3)) << 3;
    const unsigned short* ga = A + (size_t)(m0 + (w << 5) + srow) * K + scol;
    const unsigned short* gb = Bm + (size_t)(n0 + (w << 5) + srow) * K + scol;
    int ldst0 = (w * 16) * 64;            // ushorts; instr j adds j*8*64
    int ldst1 = (w * 16 + 8) * 64;

    floatx4 acc[4][4];
    #pragma unroll
    for (int mt = 0; mt < 4; ++mt)
        #pragma unroll
        for (int nt = 0; nt < 4; ++nt)
            acc[mt][nt] = (floatx4){0.f, 0.f, 0.f, 0.f};

    // swizzled read base (ushorts): row r=wm*64+mt*16+q16, chunk quad
    int abase = (wm * 32 + (q16 >> 1)) * 64 + (q16 & 1) * 32
              + ((quad ^ ((q16 >> 1) & 3)) << 3);
    int bbase = (wn * 32 + (q16 >> 1)) * 64 + (q16 & 1) * 32
              + ((quad ^ ((q16 >> 1) & 3)) << 3);

    // prologue: stage tiles 0,1,2 into buffers 0,1,2 (12 loads in flight)
    #pragma unroll
    for (int p = 0; p < 3; ++p) {
        gld_lds16(ga + p * 32, &As[p][ldst0]);
        gld_lds16(ga + p * 32 + (size_t)16 * K, &As[p][ldst1]);
        gld_lds16(gb + p * 32, &Bs[p][ldst0]);
        gld_lds16(gb + p * 32 + (size_t)16 * K, &Bs[p][ldst1]);
    }

    int cb = 0;
    for (int kt = 0; kt < NIT; ++kt) {
        // retire own tile-kt loads (4 oldest); keep the rest in flight
        if (kt < NIT - 2)       asm volatile("s_waitcnt vmcnt(8)" ::: "memory");
        else if (kt == NIT - 2) asm volatile("s_waitcnt vmcnt(4)" ::: "memory");
        else                    asm volatile("s_waitcnt vmcnt(0)" ::: "memory");
        BARE_BARRIER();                   // B1: tile kt resident in LDS

        const unsigned short* curA = &As[cb][0];
        const unsigned short* curB = &Bs[cb][0];
        short8 af[4], bf[4];
        #pragma unroll
        for (int mt = 0; mt < 4; ++mt)
            af[mt] = *(const short8*)&curA[abase + mt * 512];
        #pragma unroll
        for (int nt = 0; nt < 4; ++nt)
            bf[nt] = *(const short8*)&curB[bbase + nt * 512];

        #pragma unroll
        for (int mt = 0; mt < 4; ++mt)
            #pragma unroll
            for (int nt = 0; nt < 4; ++nt)
                acc[mt][nt] = __builtin_amdgcn_mfma_f32_16x16x32_bf16(
                    af[mt], bf[nt], acc[mt][nt], 0, 0, 0);

        asm volatile("s_waitcnt lgkmcnt(0)" ::: "memory");
        BARE_BARRIER();                   // B2: all reads of buf cb complete

        if (kt + 3 < NIT) {               // stage tile kt+3 into freed buffer
            const unsigned short* ga2 = ga + (kt + 3) * 32;
            const unsigned short* gb2 = gb + (kt + 3) * 32;
            gld_lds16(ga2, &As[cb][ldst0]);
            gld_lds16(ga2 + (size_t)16 * K, &As[cb][ldst1]);
            gld_lds16(gb2, &Bs[cb][ldst0]);
            gld_lds16(gb2 + (size_t)16 * K, &Bs[cb][ldst1]);
        }
        cb = (cb == 2) ? 0 : cb + 1;
    }

    int n_base = n0 + wn * 64;          // wave-uniform, 64-aligned
    int sec = n_base >> 10;             // 0=Q, 1=K, 2=V
    int head = (n_base & 1023) >> 6;    // 0..15

    if (sec == 2) {
        // V: vt[(b*16+head)*64 + d][s] (FP16), 4 consecutive s packed per store
        #pragma unroll
        for (int mt = 0; mt < 4; ++mt) {
            int m = m0 + wm * 64 + mt * 16 + quad * 4;
            int b = m >> 11, s = m & (S_ - 1);
            #pragma unroll
            for (int nt = 0; nt < 4; ++nt) {
                int d = nt * 16 + q16;
                unsigned short* dst =
                    vtout + ((size_t)((b * 16 + head) * 64 + d)) * S_ + s;
                uint2 pk;
                pk.x = pk_f16(acc[mt][nt][0], acc[mt][nt][1]);
                pk.y = pk_f16(acc[mt][nt][2], acc[mt][nt][3]);
                *(uint2*)dst = pk;
            }
        }
    } else {
        const float* nw = (sec == 0) ? qn_w : kn_w;
        float w4[4];
        #pragma unroll
        for (int nt = 0; nt < 4; ++nt) w4[nt] = nw[nt * 16 + q16];
        unsigned short* outp = (sec == 0) ? qout : kout;
        float qscale = (sec == 0) ? 0.1803368801111244f : 1.0f;  // (1/8)*log2e

        #pragma unroll
        for (int mt = 0; mt < 4; ++mt) {
            #pragma unroll
            for (int i = 0; i < 4; ++i) {
                int m = m0 + wm * 64 + mt * 16 + quad * 4 + i;
                int b = m >> 11, s = m & (S_ - 1);
                float v0 = acc[mt][0][i], v1 = acc[mt][1][i];
                float v2 = acc[mt][2][i], v3 = acc[mt][3][i];
                float s1 = (v0 + v1) + (v2 + v3);
                float s2 = (v0 * v0 + v1 * v1) + (v2 * v2 + v3 * v3);
                #pragma unroll
                for (int msk = 1; msk < 16; msk <<= 1) {
                    s1 += __shfl_xor(s1, msk);
                    s2 += __shfl_xor(s2, msk);
                }
                float mean = s1 * (1.f / 64);
                float var  = s2 * (1.f / 64) - mean * mean;
                float rstd = rsqrtf(var + EPS_);
                float vv[4];
                vv[0] = (v0 - mean) * rstd * w4[0];
                vv[1] = (v1 - mean) * rstd * w4[1];
                vv[2] = (v2 - mean) * rstd * w4[2];
                vv[3] = (v3 - mean) * rstd * w4[3];
                const float* fr = freqs + (size_t)s * 64;
                unsigned short* orow = outp + ((size_t)((b * 16 + head) * S_ + s)) * 64;
                #pragma unroll
                for (int nt = 0; nt < 4; ++nt) {
                    int c = nt * 16 + q16;
                    float vp = __shfl_xor(vv[nt], 1);
                    float2 ff = *(const float2*)(fr + (c & ~1));
                    float r = (c & 1) ? (vv[nt] * ff.x + vp * ff.y)
                                      : (vv[nt] * ff.x - vp * ff.y);
                    orow[c] = f2bf(r * qscale);
                }
            }
        }
    }
}

// ---------------------------------------------------------------------------
// Kernel 6: bf16 MFMA GEMM  C[M,N] = A[M,K] @ B[N,K]^T, fp32 out with
// per-(batch,col) gate. 128x64 tiles (512 blocks), T4 counted-vmcnt
// 3-buffer pipeline, bare barriers (no sched pinning).
// ---------------------------------------------------------------------------
__global__ __launch_bounds__(256) void gemm_bt_bf16_kernel(
    const unsigned short* __restrict__ A, const unsigned short* __restrict__ Bm,
    float* __restrict__ C, int M, int N, int K,
    const float* __restrict__ gate, int gate_stride, int batch_shift)
{
    __shared__ unsigned short As[3][128 * 32];
    __shared__ unsigned short Bs[3][64 * 32];
    const int NIT = 1024 / 32;            // K = 1024
    int t = threadIdx.x;
    int w = t >> 6, lane = t & 63;
    int q16 = lane & 15, quad = lane >> 4;
    int m0 = blockIdx.y * 128, n0 = blockIdx.x * 64;

    int srow = 2 * (lane >> 3) + ((lane >> 2) & 1);
    int scol = ((lane & 3) ^ ((lane >> 3) & 3)) << 3;
    // A: wave w stages rows 32w..32w+31 (2 instrs); B: rows 16w..16w+15 (1)
    const unsigned short* ga = A + (size_t)(m0 + (w << 5) + srow) * K + scol;
    const unsigned short* gb = Bm + (size_t)(n0 + (w << 4) + srow) * K + scol;
    int ldstA0 = (w * 16) * 64;
    int ldstA1 = (w * 16 + 8) * 64;
    int ldstB  = (w * 8) * 64;

    floatx4 acc[2][4];
    #pragma unroll
    for (int mt = 0; mt < 2; ++mt)
        #pragma unroll
        for (int nt = 0; nt < 4; ++nt)
            acc[mt][nt] = (floatx4){0.f, 0.f, 0.f, 0.f};

    // read bases: A row = w*32 + mt*16 + q16; B row = nt*16 + q16
    int abase = (w * 16 + (q16 >> 1)) * 64 + (q16 & 1) * 32
              + ((quad ^ ((q16 >> 1) & 3)) << 3);
    int bbase = (q16 >> 1) * 64 + (q16 & 1) * 32
              + ((quad ^ ((q16 >> 1) & 3)) << 3);

    #pragma unroll
    for (int p = 0; p < 3; ++p) {
        gld_lds16(ga + p * 32, &As[p][ldstA0]);
        gld_lds16(ga + p * 32 + (size_t)16 * K, &As[p][ldstA1]);
        gld_lds16(gb + p * 32, &Bs[p][ldstB]);
    }

    int cb = 0;
    for (int kt = 0; kt < NIT; ++kt) {
        if (kt < NIT - 2)       asm volatile("s_waitcnt vmcnt(6)" ::: "memory");
        else if (kt == NIT - 2) asm volatile("s_waitcnt vmcnt(3)" ::: "memory");
        else                    asm volatile("s_waitcnt vmcnt(0)" ::: "memory");
        BARE_BARRIER();                   // B1: tile kt resident

        const unsigned short* curA = &As[cb][0];
        const unsigned short* curB = &Bs[cb][0];
        short8 af[2], bf[4];
        #pragma unroll
        for (int mt = 0; mt < 2; ++mt)
            af[mt] = *(const short8*)&curA[abase + mt * 512];
        #pragma unroll
        for (int nt = 0; nt < 4; ++nt)
            bf[nt] = *(const short8*)&curB[bbase + nt * 512];

        #pragma unroll
        for (int mt = 0; mt < 2; ++mt)
            #pragma unroll
            for (int nt = 0; nt < 4; ++nt)
                acc[mt][nt] = __builtin_amdgcn_mfma_f32_16x16x32_bf16(
                    af[mt], bf[nt], acc[mt][nt], 0, 0, 0);

        asm volatile("s_waitcnt lgkmcnt(0)" ::: "memory");
        BARE_BARRIER();                   // B2: reads of buf cb complete

        if (kt + 3 < NIT) {
            const unsigned short* ga2 = ga + (kt + 3) * 32;
            const unsigned short* gb2 = gb + (kt + 3) * 32;
            gld_lds16(ga2, &As[cb][ldstA0]);
            gld_lds16(ga2 + (size_t)16 * K, &As[cb][ldstA1]);
            gld_lds16(gb2, &Bs[cb][ldstB]);
        }
        cb = (cb == 2) ? 0 : cb + 1;
    }

    #pragma unroll
    for (int mt = 0; mt < 2; ++mt) {
        #pragma unroll
        for (int i = 0; i < 4; ++i) {
            int m = m0 + w * 32 + mt * 16 + quad * 4 + i;
            float* crow = C + (size_t)m * N;
            const float* grow = gate ? gate + (size_t)(m >> batch_shift) * gate_stride
                                     : nullptr;
            #pragma unroll
            for (int nt = 0; nt < 4; ++nt) {
                int n = n0 + nt * 16 + q16;
                float v = acc[mt][nt][i];
                if (gate) v *= grow[n];
                crow[n] = v;
            }
        }
    }
}

// ---------------------------------------------------------------------------
// Kernel 5: bf16/f16-MFMA flash attention, STATIC-shift softmax.
// R9-verified winner — byte-identical. Key-split + dbuf-V, raw barriers;
// K/V global->reg prefetches survive the barrier (no vmcnt(0) drain).
// ---------------------------------------------------------------------------
__global__ __launch_bounds__(256, 2) void attn_mfma_kernel(
    const unsigned short* __restrict__ q, const unsigned short* __restrict__ k,
    const unsigned short* __restrict__ vt, unsigned short* __restrict__ o)
{
    __shared__ __align__(16) unsigned char smem[16 * 1024]; // Vs[2] (8K each) / obuf
    __shared__ float lbuf[4][4][16];
    unsigned short* Vs = (unsigned short*)smem;   // swizzled [64 d][64 k] f16, x2

    int t = threadIdx.x;
    int w = t >> 6, lane = t & 63;
    int q16 = lane & 15, quad = lane >> 4;
    int bh = blockIdx.y, b = bh >> 4, h = bh & 15;
    int s0 = blockIdx.x * 64;

    // ---- Q fragments: all 64 queries, B-operand layout (row=q16, k=quad*8+j)
    const unsigned short* qgp = q + ((size_t)bh * S_ + s0) * HD_;
    short8 qf[4][2];
    #pragma unroll
    for (int qg = 0; qg < 4; ++qg)
        #pragma unroll
        for (int hh = 0; hh < 2; ++hh)
            qf[qg][hh] = *(const short8*)(qgp + (16 * qg + q16) * HD_ + hh * 32 + quad * 8);

    // ---- K fragment source: wave w owns keys 16w..16w+15 (A-layout direct)
    const unsigned short* kg = k + (size_t)bh * S_ * HD_ + (16 * w + q16) * HD_ + quad * 8;

    // ---- V staging: wave w stages d-rows [16w,16w+16); swizzled write addrs
    const unsigned short* vg0 = vt + (size_t)bh * 64 * S_
                              + (size_t)(16 * w + (lane >> 3)) * S_ + (lane & 7) * 8;
    const unsigned short* vg1 = vg0 + 8 * S_;
    unsigned short* vw0 = Vs + (16 * w + (lane >> 3)) * 64 + (((lane & 7) ^ (lane >> 3)) << 3);
    unsigned short* vw1 = vw0 + 512;
    // swizzled read offset (nd-independent part): row=q16 (+16nd), keys 16w+4quad..+3
    int vroff = q16 * 64 + (((2 * w + (quad >> 1)) ^ (q16 & 7)) << 3) + ((quad & 1) << 2);

    const int NT = S_ / 64;

    // prologue: K(0) + V(0) in flight
    short8 kf_nx0 = *(const short8*)kg;
    short8 kf_nx1 = *(const short8*)(kg + 32);
    uint4 vr0 = *(const uint4*)vg0;
    uint4 vr1 = *(const uint4*)vg1;
    vg0 += 64; vg1 += 64;

    // write V(0) -> buf0 (waits on vr), then issue V(1) loads
    *(uint4*)vw0 = vr0;
    *(uint4*)vw1 = vr1;
    vr0 = *(const uint4*)vg0;
    vr1 = *(const uint4*)vg1;
    vg0 += 64; vg1 += 64;
    asm volatile("s_waitcnt lgkmcnt(0)" ::: "memory");
    RAW_BARRIER();                        // buf0 ready (V(1) loads in flight)

    // f16 ones A-fragment for the l-row MFMA
    union { half4v h; uint2 u; } ones;
    ones.u.x = 0x3C003C00u; ones.u.y = 0x3C003C00u;

    floatx4 acc_o[4][4];   // [nd][qg]: O^T[d=16nd+4quad+i][q=16qg+q16] partial
    floatx4 acc_l[4];      // [qg]: row sums of P (all rows identical)
    #pragma unroll
    for (int nd = 0; nd < 4; ++nd)
        #pragma unroll
        for (int qg = 0; qg < 4; ++qg)
            acc_o[nd][qg] = (floatx4){0.f, 0.f, 0.f, 0.f};
    #pragma unroll
    for (int qg = 0; qg < 4; ++qg) acc_l[qg] = (floatx4){0.f, 0.f, 0.f, 0.f};

    int cur = 0;
    for (int kt = 0; kt < NT; ++kt) {
        short8 kf0 = kf_nx0, kf1 = kf_nx1;   // waits on prefetched K(kt)

        if (kt + 1 < NT) {
            // write V(kt+1) -> buf^1 (waits on vr); prev barrier protects buf^1
            int nb = cur ^ 1;
            *(uint4*)(vw0 + nb * 4096) = vr0;
            *(uint4*)(vw1 + nb * 4096) = vr1;
            // issue K(kt+1) and V(kt+2) loads; fly across the barrier below
            kg += 64 * HD_;
            kf_nx0 = *(const short8*)kg;
            kf_nx1 = *(const short8*)(kg + 32);
            if (kt + 2 < NT) {
                vr0 = *(const uint4*)vg0;
                vr1 = *(const uint4*)vg1;
                vg0 += 64; vg1 += 64;
            }
        }

        // QK^T: S^T[key=quad*4+i][q=q16] per qg; C-init = -12 (static shift)
        floatx4 sc[4];
        #pragma unroll
        for (int qg = 0; qg < 4; ++qg) sc[qg] = (floatx4){-12.f, -12.f, -12.f, -12.f};
        #pragma unroll
        for (int qg = 0; qg < 4; ++qg) {
            sc[qg] = __builtin_amdgcn_mfma_f32_16x16x32_bf16(kf0, qf[qg][0], sc[qg], 0, 0, 0);
            sc[qg] = __builtin_amdgcn_mfma_f32_16x16x32_bf16(kf1, qf[qg][1], sc[qg], 0, 0, 0);
        }

        // V fragments from buf[cur] (A-layout for 16x16x16: row=16nd+q16)
        const unsigned short* vbase = Vs + cur * 4096;
        half4v vf[4];
        #pragma unroll
        for (int nd = 0; nd < 4; ++nd)
            vf[nd] = *(const half4v*)&vbase[vroff + nd * 1024];

        // p = exp2(sc); pack in-register into the PV B-fragment (k=quad*4+j)
        #pragma unroll
        for (int qg = 0; qg < 4; ++qg) {
            float p0 = __builtin_amdgcn_exp2f(sc[qg][0]);
            float p1 = __builtin_amdgcn_exp2f(sc[qg][1]);
            float p2 = __builtin_amdgcn_exp2f(sc[qg][2]);
            float p3 = __builtin_amdgcn_exp2f(sc[qg][3]);
            union { half4v h; fp16x2 f2[2]; } pf;
            pf.f2[0] = __builtin_amdgcn_cvt_pkrtz(p0, p1);
            pf.f2[1] = __builtin_amdgcn_cvt_pkrtz(p2, p3);
            acc_l[qg] = __builtin_amdgcn_mfma_f32_16x16x16f16(ones.h, pf.h, acc_l[qg], 0, 0, 0);
            #pragma unroll
            for (int nd = 0; nd < 4; ++nd)
                acc_o[nd][qg] = __builtin_amdgcn_mfma_f32_16x16x16f16(
                    vf[nd], pf.h, acc_o[nd][qg], 0, 0, 0);
        }

        // publish buf^1 ds_writes + retire buf[cur] ds_reads; K/V global
        // prefetches stay in flight across the raw barrier
        asm volatile("s_waitcnt lgkmcnt(0)" ::: "memory");
        RAW_BARRIER();
        cur ^= 1;
    }

    // ---- epilogue: cross-wave reduction of l then O (wave w owns qg = w)
    if (quad == 0) {
        #pragma unroll
        for (int qg = 0; qg < 4; ++qg) lbuf[w][qg][q16] = acc_l[qg][0];
    }
    __syncthreads();
    float linv = 1.f / (lbuf[0][w][q16] + lbuf[1][w][q16] + lbuf[2][w][q16] + lbuf[3][w][q16]);

    float* obuf = (float*)smem;
    float* myw = obuf + ((w * 4) * 64 + lane) * 4;   // + qg*256
    float* myr = obuf + (w * 64 + lane) * 4;         // + wsrc*1024
    unsigned short* og = o + ((size_t)(b * S_ + s0 + 16 * w + q16)) * H_ + h * HD_ + 4 * quad;

    #pragma unroll
    for (int nd = 0; nd < 4; ++nd) {
        __syncthreads();                              // obuf free
        #pragma unroll
        for (int qg = 0; qg < 4; ++qg)
            *(floatx4*)(myw + qg * 256) = acc_o[nd][qg];
        __syncthreads();
        floatx4 r0 = *(const floatx4*)(myr);
        floatx4 r1 = *(const floatx4*)(myr + 1024);
        floatx4 r2 = *(const floatx4*)(myr + 2048);
        floatx4 r3 = *(const floatx4*)(myr + 3072);
        floatx4 s = (r0 + r1) + (r2 + r3);
        uint2 pk;
        pk.x = pk_bf16(s[0] * linv, s[1] * linv);
        pk.y = pk_bf16(s[2] * linv, s[3] * linv);
        *(uint2*)(og + nd * 16) = pk;
    }
}

// ---------------------------------------------------------------------------
extern "C" void kernel_launch(void* const* d_in, const int* in_sizes, int n_in,
                              void* d_out, int out_size, void* d_ws, size_t ws_size,
                              hipStream_t stream)
{
    const float* x     = (const float*)d_in[0];
    const float* ada   = (const float*)d_in[1];
    const float* freqs = (const float*)d_in[2];
    const float* w_qkv = (const float*)d_in[3];
    const float* w_o   = (const float*)d_in[4];
    const float* ln_w  = (const float*)d_in[5];
    const float* mod_w = (const float*)d_in[6];
    const float* mod_b = (const float*)d_in[7];
    const float* qn_w  = (const float*)d_in[8];
    const float* kn_w  = (const float*)d_in[9];
    float* out = (float*)d_out;

    float* ws  = (float*)d_ws;
    float* mod = ws;                                    // 6144 f (pad to 8192)
    unsigned short* hb    = (unsigned short*)(mod + 8192);   // B*S*H bf16
    unsigned short* qb    = hb + (size_t)B_ * S_ * H_;
    unsigned short* kb    = qb + (size_t)B_ * S_ * H_;
    unsigned short* vtb   = kb + (size_t)B_ * S_ * H_;
    unsigned short* ob    = vtb + (size_t)B_ * S_ * H_;
    unsigned short* wqkvb = ob + (size_t)B_ * S_ * H_;
    unsigned short* wob   = wqkvb + (size_t)H3_ * H_;

    cast_bf16_kernel<<<H3_ * H_ / (8 * 256), 256, 0, stream>>>(w_qkv, wqkvb, H3_ * H_);
    cast_bf16_kernel<<<H_ * H_ / (8 * 256), 256, 0, stream>>>(w_o, wob, H_ * H_);
    mod_gemv_kernel<<<B_ * H3_ / 4, 256, 0, stream>>>(ada, mod_w, mod_b, mod);
    ln_mod_kernel<<<B_ * S_, 256, 0, stream>>>(x, ln_w, mod, hb);
    gemm_qkv_fused_kernel<<<dim3(H3_ / 128, B_ * S_ / 128), 256, 0, stream>>>(
        hb, wqkvb, freqs, qn_w, kn_w, qb, kb, vtb);
    attn_mfma_kernel<<<dim3(S_ / 64, B_ * NH_), 256, 0, stream>>>(qb, kb, vtb, ob);
    gemm_bt_bf16_kernel<<<dim3(H_ / 64, B_ * S_ / 128), 256, 0, stream>>>(
        ob, wob, out, B_ * S_, H_, H_, mod + 2 * H_, H3_, 11);
}

// Round 11
// 243.976 us; speedup vs baseline: 1.0432x; 1.0432x over previous
//
#include <hip/hip_runtime.h>
#include <hip/hip_bf16.h>
#include <hip/hip_fp16.h>
#include <math.h>

// Problem constants
#define B_ 2
#define S_ 2048
#define H_ 1024
#define A_ 1024
#define NH_ 16
#define HD_ 64
#define H3_ 3072
#define EPS_ 1e-5f

typedef __attribute__((ext_vector_type(8))) short short8;   // 8 bf16 in 4 VGPRs
typedef __attribute__((ext_vector_type(4))) float floatx4;  // MFMA accumulator
typedef __attribute__((ext_vector_type(4))) _Float16 half4v; // 4 f16 in 2 VGPRs
typedef __attribute__((ext_vector_type(2))) __fp16 fp16x2;   // cvt_pkrtz result type

__device__ inline unsigned short f2bf(float x) {
    union { float f; unsigned u; } v; v.f = x;
    unsigned r = v.u + 0x7fffu + ((v.u >> 16) & 1u);   // RNE
    return (unsigned short)(r >> 16);
}

// packed f32x2 -> bf16x2 (v_cvt_pk_bf16_f32 on gfx950)
__device__ inline unsigned pk_bf16(float a, float b) {
    union { __hip_bfloat162 h; unsigned u; } v;
    v.h = __float22bfloat162_rn(make_float2(a, b));
    return v.u;
}

// packed f32x2 -> f16x2 (RNE)
__device__ inline unsigned pk_f16(float a, float b) {
    union { __half2 h; unsigned u; } v;
    v.h = __float22half2_rn(make_float2(a, b));
    return v.u;
}

// async global->LDS, 16B per lane; LDS dst must be wave-uniform base + lane*16
__device__ inline void gld_lds16(const void* g, void* l) {
    __builtin_amdgcn_global_load_lds(
        (const __attribute__((address_space(1))) unsigned int*)g,
        (__attribute__((address_space(3))) unsigned int*)l, 16, 0, 0);
}

// BARE s_barrier everywhere (m141 lesson; R10 verified LDS ops chain through
// the barrier intrinsic). Ordering is carried by the "memory"-clobbered
// inline waitcnts preceding each barrier.
#define BARE_BARRIER() __builtin_amdgcn_s_barrier()

// ---------------------------------------------------------------------------
// Kernel 0: fp32 -> bf16 cast (weights), 8 elems/thread
// ---------------------------------------------------------------------------
__global__ __launch_bounds__(256) void cast_bf16_kernel(
    const float* __restrict__ in, unsigned short* __restrict__ out, int n)
{
    int i = (blockIdx.x * 256 + threadIdx.x) * 8;
    if (i >= n) return;
    float4 a = *(const float4*)(in + i);
    float4 b = *(const float4*)(in + i + 4);
    uint4 o;
    o.x = pk_bf16(a.x, a.y);
    o.y = pk_bf16(a.z, a.w);
    o.z = pk_bf16(b.x, b.y);
    o.w = pk_bf16(b.z, b.w);
    *(uint4*)(out + i) = o;
}

// ---------------------------------------------------------------------------
// Kernel 1: mod = silu(ada_cond) @ mod_w^T + mod_b     [B, 3H]
// ---------------------------------------------------------------------------
__global__ __launch_bounds__(256) void mod_gemv_kernel(
    const float* __restrict__ ada, const float* __restrict__ mod_w,
    const float* __restrict__ mod_b, float* __restrict__ mod)
{
    int wid = threadIdx.x >> 6;
    int lane = threadIdx.x & 63;
    int idx = blockIdx.x * 4 + wid;       // 0 .. B*3H-1
    int b = idx / H3_;
    int j = idx % H3_;
    const float* ar = ada + (size_t)b * A_;
    const float* wr = mod_w + (size_t)j * A_;
    float acc = 0.f;
    for (int a = lane; a < A_; a += 64) {
        float av = ar[a];
        float sv = av / (1.f + __expf(-av));   // silu
        acc += sv * wr[a];
    }
    #pragma unroll
    for (int m = 1; m < 64; m <<= 1) acc += __shfl_xor(acc, m);
    if (lane == 0) mod[idx] = acc + mod_b[j];
}

// ---------------------------------------------------------------------------
// Kernel 2: h = layernorm(x)*ln_w * (scale+1) + shift -> bf16  [B,S,H]
// ---------------------------------------------------------------------------
__global__ __launch_bounds__(256) void ln_mod_kernel(
    const float* __restrict__ x, const float* __restrict__ ln_w,
    const float* __restrict__ mod, unsigned short* __restrict__ hout)
{
    int row = blockIdx.x;          // over B*S
    int b = row >> 11;             // row / 2048
    const float* xr = x + (size_t)row * H_;
    int t = threadIdx.x;
    float4 xv = *(const float4*)(xr + t * 4);
    float s1 = xv.x + xv.y + xv.z + xv.w;
    float s2 = xv.x*xv.x + xv.y*xv.y + xv.z*xv.z + xv.w*xv.w;
    #pragma unroll
    for (int m = 1; m < 64; m <<= 1) { s1 += __shfl_xor(s1, m); s2 += __shfl_xor(s2, m); }
    __shared__ float r1[4], r2[4];
    int wid = t >> 6, lane = t & 63;
    if (lane == 0) { r1[wid] = s1; r2[wid] = s2; }
    __syncthreads();
    s1 = r1[0] + r1[1] + r1[2] + r1[3];
    s2 = r2[0] + r2[1] + r2[2] + r2[3];
    float mean = s1 * (1.f / H_);
    float var  = s2 * (1.f / H_) - mean * mean;
    float rstd = rsqrtf(var + EPS_);
    const float* mrow = mod + (size_t)b * H3_;
    float4 wv = *(const float4*)(ln_w + t * 4);
    float4 sc = *(const float4*)(mrow + t * 4);
    float4 sh = *(const float4*)(mrow + H_ + t * 4);
    float4 hv;
    hv.x = (xv.x - mean) * rstd * wv.x * (sc.x + 1.f) + sh.x;
    hv.y = (xv.y - mean) * rstd * wv.y * (sc.y + 1.f) + sh.y;
    hv.z = (xv.z - mean) * rstd * wv.z * (sc.z + 1.f) + sh.z;
    hv.w = (xv.w - mean) * rstd * wv.w * (sc.w + 1.f) + sh.w;
    uint2 o;
    o.x = pk_bf16(hv.x, hv.y);
    o.y = pk_bf16(hv.z, hv.w);
    *(uint2*)(hout + (size_t)row * H_ + t * 4) = o;
}

// ---------------------------------------------------------------------------
// Kernel 3: QKV GEMM with FUSED qk-LN + RoPE epilogue.
// T4 counted-vmcnt 3-buffer pipeline, bare barriers (R10-verified), plus
// T5 setprio around the MFMA cluster (waves arrive at B1 staggered ->
// scheduler has roles to arbitrate).
// ---------------------------------------------------------------------------
__global__ __launch_bounds__(256) void gemm_qkv_fused_kernel(
    const unsigned short* __restrict__ A, const unsigned short* __restrict__ Bm,
    const float* __restrict__ freqs, const float* __restrict__ qn_w,
    const float* __restrict__ kn_w, unsigned short* __restrict__ qout,
    unsigned short* __restrict__ kout, unsigned short* __restrict__ vtout)
{
    __shared__ unsigned short As[3][128 * 32];
    __shared__ unsigned short Bs[3][128 * 32];
    const int K = H_;
    const int NIT = K / 32;               // 32
    int t = threadIdx.x;
    int w = t >> 6, lane = t & 63;
    int q16 = lane & 15, quad = lane >> 4;
    int wm = w >> 1, wn = w & 1;
    int m0 = blockIdx.y * 128, n0 = blockIdx.x * 128;

    // staging source (pre-swizzled): instr j covers rows w*32+j*16 .. +15
    int srow = 2 * (lane >> 3) + ((lane >> 2) & 1);
    int scol = ((lane & 3) ^ ((lane >> 3) & 3)) << 3;
    const unsigned short* ga = A + (size_t)(m0 + (w << 5) + srow) * K + scol;
    const unsigned short* gb = Bm + (size_t)(n0 + (w << 5) + srow) * K + scol;
    int ldst0 = (w * 16) * 64;            // ushorts; instr j adds j*8*64
    int ldst1 = (w * 16 + 8) * 64;

    floatx4 acc[4][4];
    #pragma unroll
    for (int mt = 0; mt < 4; ++mt)
        #pragma unroll
        for (int nt = 0; nt < 4; ++nt)
            acc[mt][nt] = (floatx4){0.f, 0.f, 0.f, 0.f};

    // swizzled read base (ushorts): row r=wm*64+mt*16+q16, chunk quad
    int abase = (wm * 32 + (q16 >> 1)) * 64 + (q16 & 1) * 32
              + ((quad ^ ((q16 >> 1) & 3)) << 3);
    int bbase = (wn * 32 + (q16 >> 1)) * 64 + (q16 & 1) * 32
              + ((quad ^ ((q16 >> 1) & 3)) << 3);

    // prologue: stage tiles 0,1,2 into buffers 0,1,2 (12 loads in flight)
    #pragma unroll
    for (int p = 0; p < 3; ++p) {
        gld_lds16(ga + p * 32, &As[p][ldst0]);
        gld_lds16(ga + p * 32 + (size_t)16 * K, &As[p][ldst1]);
        gld_lds16(gb + p * 32, &Bs[p][ldst0]);
        gld_lds16(gb + p * 32 + (size_t)16 * K, &Bs[p][ldst1]);
    }

    int cb = 0;
    for (int kt = 0; kt < NIT; ++kt) {
        // retire own tile-kt loads (4 oldest); keep the rest in flight
        if (kt < NIT - 2)       asm volatile("s_waitcnt vmcnt(8)" ::: "memory");
        else if (kt == NIT - 2) asm volatile("s_waitcnt vmcnt(4)" ::: "memory");
        else                    asm volatile("s_waitcnt vmcnt(0)" ::: "memory");
        BARE_BARRIER();                   // B1: tile kt resident in LDS

        const unsigned short* curA = &As[cb][0];
        const unsigned short* curB = &Bs[cb][0];
        short8 af[4], bf[4];
        #pragma unroll
        for (int mt = 0; mt < 4; ++mt)
            af[mt] = *(const short8*)&curA[abase + mt * 512];
        #pragma unroll
        for (int nt = 0; nt < 4; ++nt)
            bf[nt] = *(const short8*)&curB[bbase + nt * 512];

        __builtin_amdgcn_s_setprio(1);
        #pragma unroll
        for (int mt = 0; mt < 4; ++mt)
            #pragma unroll
            for (int nt = 0; nt < 4; ++nt)
                acc[mt][nt] = __builtin_amdgcn_mfma_f32_16x16x32_bf16(
                    af[mt], bf[nt], acc[mt][nt], 0, 0, 0);
        __builtin_amdgcn_s_setprio(0);

        asm volatile("s_waitcnt lgkmcnt(0)" ::: "memory");
        BARE_BARRIER();                   // B2: all reads of buf cb complete

        if (kt + 3 < NIT) {               // stage tile kt+3 into freed buffer
            const unsigned short* ga2 = ga + (kt + 3) * 32;
            const unsigned short* gb2 = gb + (kt + 3) * 32;
            gld_lds16(ga2, &As[cb][ldst0]);
            gld_lds16(ga2 + (size_t)16 * K, &As[cb][ldst1]);
            gld_lds16(gb2, &Bs[cb][ldst0]);
            gld_lds16(gb2 + (size_t)16 * K, &Bs[cb][ldst1]);
        }
        cb = (cb == 2) ? 0 : cb + 1;
    }

    int n_base = n0 + wn * 64;          // wave-uniform, 64-aligned
    int sec = n_base >> 10;             // 0=Q, 1=K, 2=V
    int head = (n_base & 1023) >> 6;    // 0..15

    if (sec == 2) {
        // V: vt[(b*16+head)*64 + d][s] (FP16), 4 consecutive s packed per store
        #pragma unroll
        for (int mt = 0; mt < 4; ++mt) {
            int m = m0 + wm * 64 + mt * 16 + quad * 4;
            int b = m >> 11, s = m & (S_ - 1);
            #pragma unroll
            for (int nt = 0; nt < 4; ++nt) {
                int d = nt * 16 + q16;
                unsigned short* dst =
                    vtout + ((size_t)((b * 16 + head) * 64 + d)) * S_ + s;
                uint2 pk;
                pk.x = pk_f16(acc[mt][nt][0], acc[mt][nt][1]);
                pk.y = pk_f16(acc[mt][nt][2], acc[mt][nt][3]);
                *(uint2*)dst = pk;
            }
        }
    } else {
        const float* nw = (sec == 0) ? qn_w : kn_w;
        float w4[4];
        #pragma unroll
        for (int nt = 0; nt < 4; ++nt) w4[nt] = nw[nt * 16 + q16];
        unsigned short* outp = (sec == 0) ? qout : kout;
        float qscale = (sec == 0) ? 0.1803368801111244f : 1.0f;  // (1/8)*log2e

        #pragma unroll
        for (int mt = 0; mt < 4; ++mt) {
            #pragma unroll
            for (int i = 0; i < 4; ++i) {
                int m = m0 + wm * 64 + mt * 16 + quad * 4 + i;
                int b = m >> 11, s = m & (S_ - 1);
                float v0 = acc[mt][0][i], v1 = acc[mt][1][i];
                float v2 = acc[mt][2][i], v3 = acc[mt][3][i];
                float s1 = (v0 + v1) + (v2 + v3);
                float s2 = (v0 * v0 + v1 * v1) + (v2 * v2 + v3 * v3);
                #pragma unroll
                for (int msk = 1; msk < 16; msk <<= 1) {
                    s1 += __shfl_xor(s1, msk);
                    s2 += __shfl_xor(s2, msk);
                }
                float mean = s1 * (1.f / 64);
                float var  = s2 * (1.f / 64) - mean * mean;
                float rstd = rsqrtf(var + EPS_);
                float vv[4];
                vv[0] = (v0 - mean) * rstd * w4[0];
                vv[1] = (v1 - mean) * rstd * w4[1];
                vv[2] = (v2 - mean) * rstd * w4[2];
                vv[3] = (v3 - mean) * rstd * w4[3];
                const float* fr = freqs + (size_t)s * 64;
                unsigned short* orow = outp + ((size_t)((b * 16 + head) * S_ + s)) * 64;
                #pragma unroll
                for (int nt = 0; nt < 4; ++nt) {
                    int c = nt * 16 + q16;
                    float vp = __shfl_xor(vv[nt], 1);
                    float2 ff = *(const float2*)(fr + (c & ~1));
                    float r = (c & 1) ? (vv[nt] * ff.x + vp * ff.y)
                                      : (vv[nt] * ff.x - vp * ff.y);
                    orow[c] = f2bf(r * qscale);
                }
            }
        }
    }
}

// ---------------------------------------------------------------------------
// Kernel 6: bf16 MFMA GEMM  C[M,N] = A[M,K] @ B[N,K]^T, fp32 out with
// per-(batch,col) gate. 128x64 tiles (512 blocks), T4 counted-vmcnt
// 3-buffer pipeline, bare barriers, T5 setprio.
// ---------------------------------------------------------------------------
__global__ __launch_bounds__(256) void gemm_bt_bf16_kernel(
    const unsigned short* __restrict__ A, const unsigned short* __restrict__ Bm,
    float* __restrict__ C, int M, int N, int K,
    const float* __restrict__ gate, int gate_stride, int batch_shift)
{
    __shared__ unsigned short As[3][128 * 32];
    __shared__ unsigned short Bs[3][64 * 32];
    const int NIT = 1024 / 32;            // K = 1024
    int t = threadIdx.x;
    int w = t >> 6, lane = t & 63;
    int q16 = lane & 15, quad = lane >> 4;
    int m0 = blockIdx.y * 128, n0 = blockIdx.x * 64;

    int srow = 2 * (lane >> 3) + ((lane >> 2) & 1);
    int scol = ((lane & 3) ^ ((lane >> 3) & 3)) << 3;
    // A: wave w stages rows 32w..32w+31 (2 instrs); B: rows 16w..16w+15 (1)
    const unsigned short* ga = A + (size_t)(m0 + (w << 5) + srow) * K + scol;
    const unsigned short* gb = Bm + (size_t)(n0 + (w << 4) + srow) * K + scol;
    int ldstA0 = (w * 16) * 64;
    int ldstA1 = (w * 16 + 8) * 64;
    int ldstB  = (w * 8) * 64;

    floatx4 acc[2][4];
    #pragma unroll
    for (int mt = 0; mt < 2; ++mt)
        #pragma unroll
        for (int nt = 0; nt < 4; ++nt)
            acc[mt][nt] = (floatx4){0.f, 0.f, 0.f, 0.f};

    // read bases: A row = w*32 + mt*16 + q16; B row = nt*16 + q16
    int abase = (w * 16 + (q16 >> 1)) * 64 + (q16 & 1) * 32
              + ((quad ^ ((q16 >> 1) & 3)) << 3);
    int bbase = (q16 >> 1) * 64 + (q16 & 1) * 32
              + ((quad ^ ((q16 >> 1) & 3)) << 3);

    #pragma unroll
    for (int p = 0; p < 3; ++p) {
        gld_lds16(ga + p * 32, &As[p][ldstA0]);
        gld_lds16(ga + p * 32 + (size_t)16 * K, &As[p][ldstA1]);
        gld_lds16(gb + p * 32, &Bs[p][ldstB]);
    }

    int cb = 0;
    for (int kt = 0; kt < NIT; ++kt) {
        if (kt < NIT - 2)       asm volatile("s_waitcnt vmcnt(6)" ::: "memory");
        else if (kt == NIT - 2) asm volatile("s_waitcnt vmcnt(3)" ::: "memory");
        else                    asm volatile("s_waitcnt vmcnt(0)" ::: "memory");
        BARE_BARRIER();                   // B1: tile kt resident

        const unsigned short* curA = &As[cb][0];
        const unsigned short* curB = &Bs[cb][0];
        short8 af[2], bf[4];
        #pragma unroll
        for (int mt = 0; mt < 2; ++mt)
            af[mt] = *(const short8*)&curA[abase + mt * 512];
        #pragma unroll
        for (int nt = 0; nt < 4; ++nt)
            bf[nt] = *(const short8*)&curB[bbase + nt * 512];

        __builtin_amdgcn_s_setprio(1);
        #pragma unroll
        for (int mt = 0; mt < 2; ++mt)
            #pragma unroll
            for (int nt = 0; nt < 4; ++nt)
                acc[mt][nt] = __builtin_amdgcn_mfma_f32_16x16x32_bf16(
                    af[mt], bf[nt], acc[mt][nt], 0, 0, 0);
        __builtin_amdgcn_s_setprio(0);

        asm volatile("s_waitcnt lgkmcnt(0)" ::: "memory");
        BARE_BARRIER();                   // B2: reads of buf cb complete

        if (kt + 3 < NIT) {
            const unsigned short* ga2 = ga + (kt + 3) * 32;
            const unsigned short* gb2 = gb + (kt + 3) * 32;
            gld_lds16(ga2, &As[cb][ldstA0]);
            gld_lds16(ga2 + (size_t)16 * K, &As[cb][ldstA1]);
            gld_lds16(gb2, &Bs[cb][ldstB]);
        }
        cb = (cb == 2) ? 0 : cb + 1;
    }

    #pragma unroll
    for (int mt = 0; mt < 2; ++mt) {
        #pragma unroll
        for (int i = 0; i < 4; ++i) {
            int m = m0 + w * 32 + mt * 16 + quad * 4 + i;
            float* crow = C + (size_t)m * N;
            const float* grow = gate ? gate + (size_t)(m >> batch_shift) * gate_stride
                                     : nullptr;
            #pragma unroll
            for (int nt = 0; nt < 4; ++nt) {
                int n = n0 + nt * 16 + q16;
                float v = acc[mt][nt][i];
                if (gate) v *= grow[n];
                crow[n] = v;
            }
        }
    }
}

// ---------------------------------------------------------------------------
// Kernel 5: bf16/f16-MFMA flash attention, STATIC-shift softmax.
// Round-18: R10 structure with BARE barriers (sched fences removed — same
// mechanism that cost qkv 12 µs in R9) + T5 setprio around the compute
// cluster. Key-split + dbuf-V; K/V global->reg prefetches survive barriers.
// ---------------------------------------------------------------------------
__global__ __launch_bounds__(256, 2) void attn_mfma_kernel(
    const unsigned short* __restrict__ q, const unsigned short* __restrict__ k,
    const unsigned short* __restrict__ vt, unsigned short* __restrict__ o)
{
    __shared__ __align__(16) unsigned char smem[16 * 1024]; // Vs[2] (8K each) / obuf
    __shared__ float lbuf[4][4][16];
    unsigned short* Vs = (unsigned short*)smem;   // swizzled [64 d][64 k] f16, x2

    int t = threadIdx.x;
    int w = t >> 6, lane = t & 63;
    int q16 = lane & 15, quad = lane >> 4;
    int bh = blockIdx.y, b = bh >> 4, h = bh & 15;
    int s0 = blockIdx.x * 64;

    // ---- Q fragments: all 64 queries, B-operand layout (row=q16, k=quad*8+j)
    const unsigned short* qgp = q + ((size_t)bh * S_ + s0) * HD_;
    short8 qf[4][2];
    #pragma unroll
    for (int qg = 0; qg < 4; ++qg)
        #pragma unroll
        for (int hh = 0; hh < 2; ++hh)
            qf[qg][hh] = *(const short8*)(qgp + (16 * qg + q16) * HD_ + hh * 32 + quad * 8);

    // ---- K fragment source: wave w owns keys 16w..16w+15 (A-layout direct)
    const unsigned short* kg = k + (size_t)bh * S_ * HD_ + (16 * w + q16) * HD_ + quad * 8;

    // ---- V staging: wave w stages d-rows [16w,16w+16); swizzled write addrs
    const unsigned short* vg0 = vt + (size_t)bh * 64 * S_
                              + (size_t)(16 * w + (lane >> 3)) * S_ + (lane & 7) * 8;
    const unsigned short* vg1 = vg0 + 8 * S_;
    unsigned short* vw0 = Vs + (16 * w + (lane >> 3)) * 64 + (((lane & 7) ^ (lane >> 3)) << 3);
    unsigned short* vw1 = vw0 + 512;
    // swizzled read offset (nd-independent part): row=q16 (+16nd), keys 16w+4quad..+3
    int vroff = q16 * 64 + (((2 * w + (quad >> 1)) ^ (q16 & 7)) << 3) + ((quad & 1) << 2);

    const int NT = S_ / 64;

    // prologue: K(0) + V(0) in flight
    short8 kf_nx0 = *(const short8*)kg;
    short8 kf_nx1 = *(const short8*)(kg + 32);
    uint4 vr0 = *(const uint4*)vg0;
    uint4 vr1 = *(const uint4*)vg1;
    vg0 += 64; vg1 += 64;

    // write V(0) -> buf0 (waits on vr), then issue V(1) loads
    *(uint4*)vw0 = vr0;
    *(uint4*)vw1 = vr1;
    vr0 = *(const uint4*)vg0;
    vr1 = *(const uint4*)vg1;
    vg0 += 64; vg1 += 64;
    asm volatile("s_waitcnt lgkmcnt(0)" ::: "memory");
    BARE_BARRIER();                       // buf0 ready (V(1) loads in flight)

    // f16 ones A-fragment for the l-row MFMA
    union { half4v h; uint2 u; } ones;
    ones.u.x = 0x3C003C00u; ones.u.y = 0x3C003C00u;

    floatx4 acc_o[4][4];   // [nd][qg]: O^T[d=16nd+4quad+i][q=16qg+q16] partial
    floatx4 acc_l[4];      // [qg]: row sums of P (all rows identical)
    #pragma unroll
    for (int nd = 0; nd < 4; ++nd)
        #pragma unroll
        for (int qg = 0; qg < 4; ++qg)
            acc_o[nd][qg] = (floatx4){0.f, 0.f, 0.f, 0.f};
    #pragma unroll
    for (int qg = 0; qg < 4; ++qg) acc_l[qg] = (floatx4){0.f, 0.f, 0.f, 0.f};

    int cur = 0;
    for (int kt = 0; kt < NT; ++kt) {
        short8 kf0 = kf_nx0, kf1 = kf_nx1;   // waits on prefetched K(kt)

        if (kt + 1 < NT) {
            // write V(kt+1) -> buf^1 (waits on vr); prev barrier protects buf^1
            int nb = cur ^ 1;
            *(uint4*)(vw0 + nb * 4096) = vr0;
            *(uint4*)(vw1 + nb * 4096) = vr1;
            // issue K(kt+1) and V(kt+2) loads; fly across the barrier below
            kg += 64 * HD_;
            kf_nx0 = *(const short8*)kg;
            kf_nx1 = *(const short8*)(kg + 32);
            if (kt + 2 < NT) {
                vr0 = *(const uint4*)vg0;
                vr1 = *(const uint4*)vg1;
                vg0 += 64; vg1 += 64;
            }
        }

        // QK^T: S^T[key=quad*4+i][q=q16] per qg; C-init = -12 (static shift)
        floatx4 sc[4];
        #pragma unroll
        for (int qg = 0; qg < 4; ++qg) sc[qg] = (floatx4){-12.f, -12.f, -12.f, -12.f};
        __builtin_amdgcn_s_setprio(1);
        #pragma unroll
        for (int qg = 0; qg < 4; ++qg) {
            sc[qg] = __builtin_amdgcn_mfma_f32_16x16x32_bf16(kf0, qf[qg][0], sc[qg], 0, 0, 0);
            sc[qg] = __builtin_amdgcn_mfma_f32_16x16x32_bf16(kf1, qf[qg][1], sc[qg], 0, 0, 0);
        }

        // V fragments from buf[cur] (A-layout for 16x16x16: row=16nd+q16)
        const unsigned short* vbase = Vs + cur * 4096;
        half4v vf[4];
        #pragma unroll
        for (int nd = 0; nd < 4; ++nd)
            vf[nd] = *(const half4v*)&vbase[vroff + nd * 1024];

        // p = exp2(sc); pack in-register into the PV B-fragment (k=quad*4+j)
        #pragma unroll
        for (int qg = 0; qg < 4; ++qg) {
            float p0 = __builtin_amdgcn_exp2f(sc[qg][0]);
            float p1 = __builtin_amdgcn_exp2f(sc[qg][1]);
            float p2 = __builtin_amdgcn_exp2f(sc[qg][2]);
            float p3 = __builtin_amdgcn_exp2f(sc[qg][3]);
            union { half4v h; fp16x2 f2[2]; } pf;
            pf.f2[0] = __builtin_amdgcn_cvt_pkrtz(p0, p1);
            pf.f2[1] = __builtin_amdgcn_cvt_pkrtz(p2, p3);
            acc_l[qg] = __builtin_amdgcn_mfma_f32_16x16x16f16(ones.h, pf.h, acc_l[qg], 0, 0, 0);
            #pragma unroll
            for (int nd = 0; nd < 4; ++nd)
                acc_o[nd][qg] = __builtin_amdgcn_mfma_f32_16x16x16f16(
                    vf[nd], pf.h, acc_o[nd][qg], 0, 0, 0);
        }
        __builtin_amdgcn_s_setprio(0);

        // publish buf^1 ds_writes + retire buf[cur] ds_reads; K/V global
        // prefetches stay in flight across the bare barrier
        asm volatile("s_waitcnt lgkmcnt(0)" ::: "memory");
        BARE_BARRIER();
        cur ^= 1;
    }

    // ---- epilogue: cross-wave reduction of l then O (wave w owns qg = w)
    if (quad == 0) {
        #pragma unroll
        for (int qg = 0; qg < 4; ++qg) lbuf[w][qg][q16] = acc_l[qg][0];
    }
    __syncthreads();
    float linv = 1.f / (lbuf[0][w][q16] + lbuf[1][w][q16] + lbuf[2][w][q16] + lbuf[3][w][q16]);

    float* obuf = (float*)smem;
    float* myw = obuf + ((w * 4) * 64 + lane) * 4;   // + qg*256
    float* myr = obuf + (w * 64 + lane) * 4;         // + wsrc*1024
    unsigned short* og = o + ((size_t)(b * S_ + s0 + 16 * w + q16)) * H_ + h * HD_ + 4 * quad;

    #pragma unroll
    for (int nd = 0; nd < 4; ++nd) {
        __syncthreads();                              // obuf free
        #pragma unroll
        for (int qg = 0; qg < 4; ++qg)
            *(floatx4*)(myw + qg * 256) = acc_o[nd][qg];
        __syncthreads();
        floatx4 r0 = *(const floatx4*)(myr);
        floatx4 r1 = *(const floatx4*)(myr + 1024);
        floatx4 r2 = *(const floatx4*)(myr + 2048);
        floatx4 r3 = *(const floatx4*)(myr + 3072);
        floatx4 s = (r0 + r1) + (r2 + r3);
        uint2 pk;
        pk.x = pk_bf16(s[0] * linv, s[1] * linv);
        pk.y = pk_bf16(s[2] * linv, s[3] * linv);
        *(uint2*)(og + nd * 16) = pk;
    }
}

// ---------------------------------------------------------------------------
extern "C" void kernel_launch(void* const* d_in, const int* in_sizes, int n_in,
                              void* d_out, int out_size, void* d_ws, size_t ws_size,
                              hipStream_t stream)
{
    const float* x     = (const float*)d_in[0];
    const float* ada   = (const float*)d_in[1];
    const float* freqs = (const float*)d_in[2];
    const float* w_qkv = (const float*)d_in[3];
    const float* w_o   = (const float*)d_in[4];
    const float* ln_w  = (const float*)d_in[5];
    const float* mod_w = (const float*)d_in[6];
    const float* mod_b = (const float*)d_in[7];
    const float* qn_w  = (const float*)d_in[8];
    const float* kn_w  = (const float*)d_in[9];
    float* out = (float*)d_out;

    float* ws  = (float*)d_ws;
    float* mod = ws;                                    // 6144 f (pad to 8192)
    unsigned short* hb    = (unsigned short*)(mod + 8192);   // B*S*H bf16
    unsigned short* qb    = hb + (size_t)B_ * S_ * H_;
    unsigned short* kb    = qb + (size_t)B_ * S_ * H_;
    unsigned short* vtb   = kb + (size_t)B_ * S_ * H_;
    unsigned short* ob    = vtb + (size_t)B_ * S_ * H_;
    unsigned short* wqkvb = ob + (size_t)B_ * S_ * H_;
    unsigned short* wob   = wqkvb + (size_t)H3_ * H_;

    cast_bf16_kernel<<<H3_ * H_ / (8 * 256), 256, 0, stream>>>(w_qkv, wqkvb, H3_ * H_);
    cast_bf16_kernel<<<H_ * H_ / (8 * 256), 256, 0, stream>>>(w_o, wob, H_ * H_);
    mod_gemv_kernel<<<B_ * H3_ / 4, 256, 0, stream>>>(ada, mod_w, mod_b, mod);
    ln_mod_kernel<<<B_ * S_, 256, 0, stream>>>(x, ln_w, mod, hb);
    gemm_qkv_fused_kernel<<<dim3(H3_ / 128, B_ * S_ / 128), 256, 0, stream>>>(
        hb, wqkvb, freqs, qn_w, kn_w, qb, kb, vtb);
    attn_mfma_kernel<<<dim3(S_ / 64, B_ * NH_), 256, 0, stream>>>(qb, kb, vtb, ob);
    gemm_bt_bf16_kernel<<<dim3(H_ / 64, B_ * S_ / 128), 256, 0, stream>>>(
        ob, wob, out, B_ * S_, H_, H_, mod + 2 * H_, H3_, 11);
}

// Round 12
// 235.319 us; speedup vs baseline: 1.0816x; 1.0368x over previous
//
#include <hip/hip_runtime.h>
#include <hip/hip_bf16.h>
#include <hip/hip_fp16.h>
#include <math.h>

// Problem constants
#define B_ 2
#define S_ 2048
#define H_ 1024
#define A_ 1024
#define NH_ 16
#define HD_ 64
#define H3_ 3072
#define EPS_ 1e-5f

typedef __attribute__((ext_vector_type(8))) short short8;   // 8 bf16 in 4 VGPRs
typedef __attribute__((ext_vector_type(4))) float floatx4;  // MFMA accumulator
typedef __attribute__((ext_vector_type(4))) _Float16 half4v; // 4 f16 in 2 VGPRs
typedef __attribute__((ext_vector_type(2))) __fp16 fp16x2;   // cvt_pkrtz result type

__device__ inline unsigned short f2bf(float x) {
    union { float f; unsigned u; } v; v.f = x;
    unsigned r = v.u + 0x7fffu + ((v.u >> 16) & 1u);   // RNE
    return (unsigned short)(r >> 16);
}

// packed f32x2 -> bf16x2 (v_cvt_pk_bf16_f32 on gfx950)
__device__ inline unsigned pk_bf16(float a, float b) {
    union { __hip_bfloat162 h; unsigned u; } v;
    v.h = __float22bfloat162_rn(make_float2(a, b));
    return v.u;
}

// packed f32x2 -> f16x2 (RNE)
__device__ inline unsigned pk_f16(float a, float b) {
    union { __half2 h; unsigned u; } v;
    v.h = __float22half2_rn(make_float2(a, b));
    return v.u;
}

// async global->LDS, 16B per lane; LDS dst must be wave-uniform base + lane*16
__device__ inline void gld_lds16(const void* g, void* l) {
    __builtin_amdgcn_global_load_lds(
        (const __attribute__((address_space(1))) unsigned int*)g,
        (__attribute__((address_space(3))) unsigned int*)l, 16, 0, 0);
}

// BARE s_barrier everywhere (m141 lesson; verified R10/R11). Ordering is
// carried by the "memory"-clobbered inline waitcnts preceding each barrier.
#define BARE_BARRIER() __builtin_amdgcn_s_barrier()

// ---------------------------------------------------------------------------
// BK=64 GEMM tile geometry (R12):
// LDS tile rows are 128 B (64 bf16). Swizzle: LDS(row r, 16B-slot s) holds
// global k-chunk c = s ^ (r&7) of row r. Staged via gld_lds16 with
// PRE-SWIZZLED global source (rule #21): within an 8-row instruction, lane L
// covers row base+(L>>3), source chunk (L&7)^((L>>3)&7). ds_read fragment
// (row r, chunk c=ks*4+quad) at slot c^(r&7): 8 lanes/slot = 2 lanes/bank
// = conflict-free (m136: 2-way is free).
// ---------------------------------------------------------------------------

// ---------------------------------------------------------------------------
// Kernel 0: fp32 -> bf16 cast (weights), 8 elems/thread
// ---------------------------------------------------------------------------
__global__ __launch_bounds__(256) void cast_bf16_kernel(
    const float* __restrict__ in, unsigned short* __restrict__ out, int n)
{
    int i = (blockIdx.x * 256 + threadIdx.x) * 8;
    if (i >= n) return;
    float4 a = *(const float4*)(in + i);
    float4 b = *(const float4*)(in + i + 4);
    uint4 o;
    o.x = pk_bf16(a.x, a.y);
    o.y = pk_bf16(a.z, a.w);
    o.z = pk_bf16(b.x, b.y);
    o.w = pk_bf16(b.z, b.w);
    *(uint4*)(out + i) = o;
}

// ---------------------------------------------------------------------------
// Kernel 1: mod = silu(ada_cond) @ mod_w^T + mod_b     [B, 3H]
// ---------------------------------------------------------------------------
__global__ __launch_bounds__(256) void mod_gemv_kernel(
    const float* __restrict__ ada, const float* __restrict__ mod_w,
    const float* __restrict__ mod_b, float* __restrict__ mod)
{
    int wid = threadIdx.x >> 6;
    int lane = threadIdx.x & 63;
    int idx = blockIdx.x * 4 + wid;       // 0 .. B*3H-1
    int b = idx / H3_;
    int j = idx % H3_;
    const float* ar = ada + (size_t)b * A_;
    const float* wr = mod_w + (size_t)j * A_;
    float acc = 0.f;
    for (int a = lane; a < A_; a += 64) {
        float av = ar[a];
        float sv = av / (1.f + __expf(-av));   // silu
        acc += sv * wr[a];
    }
    #pragma unroll
    for (int m = 1; m < 64; m <<= 1) acc += __shfl_xor(acc, m);
    if (lane == 0) mod[idx] = acc + mod_b[j];
}

// ---------------------------------------------------------------------------
// Kernel 2: h = layernorm(x)*ln_w * (scale+1) + shift -> bf16  [B,S,H]
// ---------------------------------------------------------------------------
__global__ __launch_bounds__(256) void ln_mod_kernel(
    const float* __restrict__ x, const float* __restrict__ ln_w,
    const float* __restrict__ mod, unsigned short* __restrict__ hout)
{
    int row = blockIdx.x;          // over B*S
    int b = row >> 11;             // row / 2048
    const float* xr = x + (size_t)row * H_;
    int t = threadIdx.x;
    float4 xv = *(const float4*)(xr + t * 4);
    float s1 = xv.x + xv.y + xv.z + xv.w;
    float s2 = xv.x*xv.x + xv.y*xv.y + xv.z*xv.z + xv.w*xv.w;
    #pragma unroll
    for (int m = 1; m < 64; m <<= 1) { s1 += __shfl_xor(s1, m); s2 += __shfl_xor(s2, m); }
    __shared__ float r1[4], r2[4];
    int wid = t >> 6, lane = t & 63;
    if (lane == 0) { r1[wid] = s1; r2[wid] = s2; }
    __syncthreads();
    s1 = r1[0] + r1[1] + r1[2] + r1[3];
    s2 = r2[0] + r2[1] + r2[2] + r2[3];
    float mean = s1 * (1.f / H_);
    float var  = s2 * (1.f / H_) - mean * mean;
    float rstd = rsqrtf(var + EPS_);
    const float* mrow = mod + (size_t)b * H3_;
    float4 wv = *(const float4*)(ln_w + t * 4);
    float4 sc = *(const float4*)(mrow + t * 4);
    float4 sh = *(const float4*)(mrow + H_ + t * 4);
    float4 hv;
    hv.x = (xv.x - mean) * rstd * wv.x * (sc.x + 1.f) + sh.x;
    hv.y = (xv.y - mean) * rstd * wv.y * (sc.y + 1.f) + sh.y;
    hv.z = (xv.z - mean) * rstd * wv.z * (sc.z + 1.f) + sh.z;
    hv.w = (xv.w - mean) * rstd * wv.w * (sc.w + 1.f) + sh.w;
    uint2 o;
    o.x = pk_bf16(hv.x, hv.y);
    o.y = pk_bf16(hv.z, hv.w);
    *(uint2*)(hout + (size_t)row * H_ + t * 4) = o;
}

// ---------------------------------------------------------------------------
// Kernel 3: QKV GEMM with FUSED qk-LN + RoPE epilogue.
// Round-19: BK=64 (2x MFMA per barrier interval — the work/convoy ratio is
// what sets MfmaUtil in this loop class), 2 LDS buffers (64 KB, 2 blocks/CU),
// counted vmcnt (8 loads/tile/wave: steady vmcnt(8)), bare barriers,
// stage-after-B2 (target buffer's reads provably complete), T5 setprio.
// ---------------------------------------------------------------------------
__global__ __launch_bounds__(256) void gemm_qkv_fused_kernel(
    const unsigned short* __restrict__ A, const unsigned short* __restrict__ Bm,
    const float* __restrict__ freqs, const float* __restrict__ qn_w,
    const float* __restrict__ kn_w, unsigned short* __restrict__ qout,
    unsigned short* __restrict__ kout, unsigned short* __restrict__ vtout)
{
    __shared__ unsigned short As[2][128 * 64];
    __shared__ unsigned short Bs[2][128 * 64];
    const int K = H_;
    const int NIT = K / 64;               // 16
    int t = threadIdx.x;
    int w = t >> 6, lane = t & 63;
    int q16 = lane & 15, quad = lane >> 4;
    int wm = w >> 1, wn = w & 1;
    int m0 = blockIdx.y * 128, n0 = blockIdx.x * 128;

    // staging (pre-swizzled source): instr j covers rows w*32+j*8 .. +7;
    // lane L: row +(L>>3), source chunk (L&7)^((L>>3)&7) of the 128B K-slice
    int srow = lane >> 3;
    int scol = ((lane & 7) ^ ((lane >> 3) & 7)) << 3;   // elements
    const unsigned short* ga = A + (size_t)(m0 + (w << 5) + srow) * K + scol;
    const unsigned short* gb = Bm + (size_t)(n0 + (w << 5) + srow) * K + scol;

    floatx4 acc[4][4];
    #pragma unroll
    for (int mt = 0; mt < 4; ++mt)
        #pragma unroll
        for (int nt = 0; nt < 4; ++nt)
            acc[mt][nt] = (floatx4){0.f, 0.f, 0.f, 0.f};

    // swizzled read bases (elements): row r, chunk c -> r*64 + (c^(r&7))*8
    int arow = (wm * 64 + q16) * 64;
    int brow = (wn * 64 + q16) * 64;
    int sw0 = ((quad ^ (q16 & 7)) << 3);          // ks=0: c=quad
    int sw1 = (((4 + quad) ^ (q16 & 7)) << 3);    // ks=1: c=4+quad

    // prologue: stage tiles 0,1 into buffers 0,1 (16 loads/wave in flight)
    #pragma unroll
    for (int p = 0; p < 2; ++p) {
        #pragma unroll
        for (int j = 0; j < 4; ++j) {
            gld_lds16(ga + p * 64 + (size_t)(j * 8) * K, &As[p][(w * 32 + j * 8) * 64]);
            gld_lds16(gb + p * 64 + (size_t)(j * 8) * K, &Bs[p][(w * 32 + j * 8) * 64]);
        }
    }

    for (int kt = 0; kt < NIT; ++kt) {
        int cb = kt & 1;
        // retire own tile-kt loads (8); keep tile kt+1's 8 in flight
        if (kt < NIT - 1) asm volatile("s_waitcnt vmcnt(8)" ::: "memory");
        else              asm volatile("s_waitcnt vmcnt(0)" ::: "memory");
        BARE_BARRIER();                   // B1: tile kt resident in LDS

        const unsigned short* curA = &As[cb][0];
        const unsigned short* curB = &Bs[cb][0];

        __builtin_amdgcn_s_setprio(1);
        #pragma unroll
        for (int ks = 0; ks < 2; ++ks) {
            int sw = ks ? sw1 : sw0;
            short8 af[4], bf[4];
            #pragma unroll
            for (int mt = 0; mt < 4; ++mt)
                af[mt] = *(const short8*)&curA[arow + mt * 1024 + sw];
            #pragma unroll
            for (int nt = 0; nt < 4; ++nt)
                bf[nt] = *(const short8*)&curB[brow + nt * 1024 + sw];
            #pragma unroll
            for (int mt = 0; mt < 4; ++mt)
                #pragma unroll
                for (int nt = 0; nt < 4; ++nt)
                    acc[mt][nt] = __builtin_amdgcn_mfma_f32_16x16x32_bf16(
                        af[mt], bf[nt], acc[mt][nt], 0, 0, 0);
        }
        __builtin_amdgcn_s_setprio(0);

        asm volatile("s_waitcnt lgkmcnt(0)" ::: "memory");
        BARE_BARRIER();                   // B2: all reads of buf cb complete

        if (kt + 2 < NIT) {               // stage tile kt+2 into freed buf cb
            const unsigned short* ga2 = ga + (kt + 2) * 64;
            const unsigned short* gb2 = gb + (kt + 2) * 64;
            #pragma unroll
            for (int j = 0; j < 4; ++j) {
                gld_lds16(ga2 + (size_t)(j * 8) * K, &As[cb][(w * 32 + j * 8) * 64]);
                gld_lds16(gb2 + (size_t)(j * 8) * K, &Bs[cb][(w * 32 + j * 8) * 64]);
            }
        }
    }

    int n_base = n0 + wn * 64;          // wave-uniform, 64-aligned
    int sec = n_base >> 10;             // 0=Q, 1=K, 2=V
    int head = (n_base & 1023) >> 6;    // 0..15

    if (sec == 2) {
        // V: vt[(b*16+head)*64 + d][s] (FP16), 4 consecutive s packed per store
        #pragma unroll
        for (int mt = 0; mt < 4; ++mt) {
            int m = m0 + wm * 64 + mt * 16 + quad * 4;
            int b = m >> 11, s = m & (S_ - 1);
            #pragma unroll
            for (int nt = 0; nt < 4; ++nt) {
                int d = nt * 16 + q16;
                unsigned short* dst =
                    vtout + ((size_t)((b * 16 + head) * 64 + d)) * S_ + s;
                uint2 pk;
                pk.x = pk_f16(acc[mt][nt][0], acc[mt][nt][1]);
                pk.y = pk_f16(acc[mt][nt][2], acc[mt][nt][3]);
                *(uint2*)dst = pk;
            }
        }
    } else {
        const float* nw = (sec == 0) ? qn_w : kn_w;
        float w4[4];
        #pragma unroll
        for (int nt = 0; nt < 4; ++nt) w4[nt] = nw[nt * 16 + q16];
        unsigned short* outp = (sec == 0) ? qout : kout;
        float qscale = (sec == 0) ? 0.1803368801111244f : 1.0f;  // (1/8)*log2e

        #pragma unroll
        for (int mt = 0; mt < 4; ++mt) {
            #pragma unroll
            for (int i = 0; i < 4; ++i) {
                int m = m0 + wm * 64 + mt * 16 + quad * 4 + i;
                int b = m >> 11, s = m & (S_ - 1);
                float v0 = acc[mt][0][i], v1 = acc[mt][1][i];
                float v2 = acc[mt][2][i], v3 = acc[mt][3][i];
                float s1 = (v0 + v1) + (v2 + v3);
                float s2 = (v0 * v0 + v1 * v1) + (v2 * v2 + v3 * v3);
                #pragma unroll
                for (int msk = 1; msk < 16; msk <<= 1) {
                    s1 += __shfl_xor(s1, msk);
                    s2 += __shfl_xor(s2, msk);
                }
                float mean = s1 * (1.f / 64);
                float var  = s2 * (1.f / 64) - mean * mean;
                float rstd = rsqrtf(var + EPS_);
                float vv[4];
                vv[0] = (v0 - mean) * rstd * w4[0];
                vv[1] = (v1 - mean) * rstd * w4[1];
                vv[2] = (v2 - mean) * rstd * w4[2];
                vv[3] = (v3 - mean) * rstd * w4[3];
                const float* fr = freqs + (size_t)s * 64;
                unsigned short* orow = outp + ((size_t)((b * 16 + head) * S_ + s)) * 64;
                #pragma unroll
                for (int nt = 0; nt < 4; ++nt) {
                    int c = nt * 16 + q16;
                    float vp = __shfl_xor(vv[nt], 1);
                    float2 ff = *(const float2*)(fr + (c & ~1));
                    float r = (c & 1) ? (vv[nt] * ff.x + vp * ff.y)
                                      : (vv[nt] * ff.x - vp * ff.y);
                    orow[c] = f2bf(r * qscale);
                }
            }
        }
    }
}

// ---------------------------------------------------------------------------
// Kernel 6: bf16 MFMA GEMM  C[M,N] = A[M,K] @ B[N,K]^T, fp32 out with
// per-(batch,col) gate. 128x64 tiles (512 blocks), Round-19: BK=64,
// 2 LDS buffers (48 KB, 3 blocks/CU), counted vmcnt (6 loads/tile/wave),
// bare barriers, stage-after-B2, setprio.
// ---------------------------------------------------------------------------
__global__ __launch_bounds__(256) void gemm_bt_bf16_kernel(
    const unsigned short* __restrict__ A, const unsigned short* __restrict__ Bm,
    float* __restrict__ C, int M, int N, int K,
    const float* __restrict__ gate, int gate_stride, int batch_shift)
{
    __shared__ unsigned short As[2][128 * 64];
    __shared__ unsigned short Bs[2][64 * 64];
    const int NIT = 1024 / 64;            // K = 1024 -> 16
    int t = threadIdx.x;
    int w = t >> 6, lane = t & 63;
    int q16 = lane & 15, quad = lane >> 4;
    int m0 = blockIdx.y * 128, n0 = blockIdx.x * 64;

    int srow = lane >> 3;
    int scol = ((lane & 7) ^ ((lane >> 3) & 7)) << 3;
    // A: wave w stages rows w*32..+31 (4 instrs); B: rows w*16..+15 (2 instrs)
    const unsigned short* ga = A + (size_t)(m0 + (w << 5) + srow) * K + scol;
    const unsigned short* gb = Bm + (size_t)(n0 + (w << 4) + srow) * K + scol;

    floatx4 acc[2][4];
    #pragma unroll
    for (int mt = 0; mt < 2; ++mt)
        #pragma unroll
        for (int nt = 0; nt < 4; ++nt)
            acc[mt][nt] = (floatx4){0.f, 0.f, 0.f, 0.f};

    // read bases: A row = w*32 + mt*16 + q16; B row = nt*16 + q16
    int arow = (w * 32 + q16) * 64;
    int brow = q16 * 64;
    int sw0 = ((quad ^ (q16 & 7)) << 3);
    int sw1 = (((4 + quad) ^ (q16 & 7)) << 3);

    #pragma unroll
    for (int p = 0; p < 2; ++p) {
        #pragma unroll
        for (int j = 0; j < 4; ++j)
            gld_lds16(ga + p * 64 + (size_t)(j * 8) * K, &As[p][(w * 32 + j * 8) * 64]);
        #pragma unroll
        for (int j = 0; j < 2; ++j)
            gld_lds16(gb + p * 64 + (size_t)(j * 8) * K, &Bs[p][(w * 16 + j * 8) * 64]);
    }

    for (int kt = 0; kt < NIT; ++kt) {
        int cb = kt & 1;
        if (kt < NIT - 1) asm volatile("s_waitcnt vmcnt(6)" ::: "memory");
        else              asm volatile("s_waitcnt vmcnt(0)" ::: "memory");
        BARE_BARRIER();                   // B1: tile kt resident

        const unsigned short* curA = &As[cb][0];
        const unsigned short* curB = &Bs[cb][0];

        __builtin_amdgcn_s_setprio(1);
        #pragma unroll
        for (int ks = 0; ks < 2; ++ks) {
            int sw = ks ? sw1 : sw0;
            short8 af[2], bf[4];
            #pragma unroll
            for (int mt = 0; mt < 2; ++mt)
                af[mt] = *(const short8*)&curA[arow + mt * 1024 + sw];
            #pragma unroll
            for (int nt = 0; nt < 4; ++nt)
                bf[nt] = *(const short8*)&curB[brow + nt * 1024 + sw];
            #pragma unroll
            for (int mt = 0; mt < 2; ++mt)
                #pragma unroll
                for (int nt = 0; nt < 4; ++nt)
                    acc[mt][nt] = __builtin_amdgcn_mfma_f32_16x16x32_bf16(
                        af[mt], bf[nt], acc[mt][nt], 0, 0, 0);
        }
        __builtin_amdgcn_s_setprio(0);

        asm volatile("s_waitcnt lgkmcnt(0)" ::: "memory");
        BARE_BARRIER();                   // B2: reads of buf cb complete

        if (kt + 2 < NIT) {
            const unsigned short* ga2 = ga + (kt + 2) * 64;
            const unsigned short* gb2 = gb + (kt + 2) * 64;
            #pragma unroll
            for (int j = 0; j < 4; ++j)
                gld_lds16(ga2 + (size_t)(j * 8) * K, &As[cb][(w * 32 + j * 8) * 64]);
            #pragma unroll
            for (int j = 0; j < 2; ++j)
                gld_lds16(gb2 + (size_t)(j * 8) * K, &Bs[cb][(w * 16 + j * 8) * 64]);
        }
    }

    #pragma unroll
    for (int mt = 0; mt < 2; ++mt) {
        #pragma unroll
        for (int i = 0; i < 4; ++i) {
            int m = m0 + w * 32 + mt * 16 + quad * 4 + i;
            float* crow = C + (size_t)m * N;
            const float* grow = gate ? gate + (size_t)(m >> batch_shift) * gate_stride
                                     : nullptr;
            #pragma unroll
            for (int nt = 0; nt < 4; ++nt) {
                int n = n0 + nt * 16 + q16;
                float v = acc[mt][nt][i];
                if (gate) v *= grow[n];
                crow[n] = v;
            }
        }
    }
}

// ---------------------------------------------------------------------------
// Kernel 5: bf16/f16-MFMA flash attention, STATIC-shift softmax.
// R11-verified winner — byte-identical. Key-split + dbuf-V, bare barriers,
// setprio; K/V global->reg prefetches survive barriers.
// ---------------------------------------------------------------------------
__global__ __launch_bounds__(256, 2) void attn_mfma_kernel(
    const unsigned short* __restrict__ q, const unsigned short* __restrict__ k,
    const unsigned short* __restrict__ vt, unsigned short* __restrict__ o)
{
    __shared__ __align__(16) unsigned char smem[16 * 1024]; // Vs[2] (8K each) / obuf
    __shared__ float lbuf[4][4][16];
    unsigned short* Vs = (unsigned short*)smem;   // swizzled [64 d][64 k] f16, x2

    int t = threadIdx.x;
    int w = t >> 6, lane = t & 63;
    int q16 = lane & 15, quad = lane >> 4;
    int bh = blockIdx.y, b = bh >> 4, h = bh & 15;
    int s0 = blockIdx.x * 64;

    // ---- Q fragments: all 64 queries, B-operand layout (row=q16, k=quad*8+j)
    const unsigned short* qgp = q + ((size_t)bh * S_ + s0) * HD_;
    short8 qf[4][2];
    #pragma unroll
    for (int qg = 0; qg < 4; ++qg)
        #pragma unroll
        for (int hh = 0; hh < 2; ++hh)
            qf[qg][hh] = *(const short8*)(qgp + (16 * qg + q16) * HD_ + hh * 32 + quad * 8);

    // ---- K fragment source: wave w owns keys 16w..16w+15 (A-layout direct)
    const unsigned short* kg = k + (size_t)bh * S_ * HD_ + (16 * w + q16) * HD_ + quad * 8;

    // ---- V staging: wave w stages d-rows [16w,16w+16); swizzled write addrs
    const unsigned short* vg0 = vt + (size_t)bh * 64 * S_
                              + (size_t)(16 * w + (lane >> 3)) * S_ + (lane & 7) * 8;
    const unsigned short* vg1 = vg0 + 8 * S_;
    unsigned short* vw0 = Vs + (16 * w + (lane >> 3)) * 64 + (((lane & 7) ^ (lane >> 3)) << 3);
    unsigned short* vw1 = vw0 + 512;
    // swizzled read offset (nd-independent part): row=q16 (+16nd), keys 16w+4quad..+3
    int vroff = q16 * 64 + (((2 * w + (quad >> 1)) ^ (q16 & 7)) << 3) + ((quad & 1) << 2);

    const int NT = S_ / 64;

    // prologue: K(0) + V(0) in flight
    short8 kf_nx0 = *(const short8*)kg;
    short8 kf_nx1 = *(const short8*)(kg + 32);
    uint4 vr0 = *(const uint4*)vg0;
    uint4 vr1 = *(const uint4*)vg1;
    vg0 += 64; vg1 += 64;

    // write V(0) -> buf0 (waits on vr), then issue V(1) loads
    *(uint4*)vw0 = vr0;
    *(uint4*)vw1 = vr1;
    vr0 = *(const uint4*)vg0;
    vr1 = *(const uint4*)vg1;
    vg0 += 64; vg1 += 64;
    asm volatile("s_waitcnt lgkmcnt(0)" ::: "memory");
    BARE_BARRIER();                       // buf0 ready (V(1) loads in flight)

    // f16 ones A-fragment for the l-row MFMA
    union { half4v h; uint2 u; } ones;
    ones.u.x = 0x3C003C00u; ones.u.y = 0x3C003C00u;

    floatx4 acc_o[4][4];   // [nd][qg]: O^T[d=16nd+4quad+i][q=16qg+q16] partial
    floatx4 acc_l[4];      // [qg]: row sums of P (all rows identical)
    #pragma unroll
    for (int nd = 0; nd < 4; ++nd)
        #pragma unroll
        for (int qg = 0; qg < 4; ++qg)
            acc_o[nd][qg] = (floatx4){0.f, 0.f, 0.f, 0.f};
    #pragma unroll
    for (int qg = 0; qg < 4; ++qg) acc_l[qg] = (floatx4){0.f, 0.f, 0.f, 0.f};

    int cur = 0;
    for (int kt = 0; kt < NT; ++kt) {
        short8 kf0 = kf_nx0, kf1 = kf_nx1;   // waits on prefetched K(kt)

        if (kt + 1 < NT) {
            // write V(kt+1) -> buf^1 (waits on vr); prev barrier protects buf^1
            int nb = cur ^ 1;
            *(uint4*)(vw0 + nb * 4096) = vr0;
            *(uint4*)(vw1 + nb * 4096) = vr1;
            // issue K(kt+1) and V(kt+2) loads; fly across the barrier below
            kg += 64 * HD_;
            kf_nx0 = *(const short8*)kg;
            kf_nx1 = *(const short8*)(kg + 32);
            if (kt + 2 < NT) {
                vr0 = *(const uint4*)vg0;
                vr1 = *(const uint4*)vg1;
                vg0 += 64; vg1 += 64;
            }
        }

        // QK^T: S^T[key=quad*4+i][q=q16] per qg; C-init = -12 (static shift)
        floatx4 sc[4];
        #pragma unroll
        for (int qg = 0; qg < 4; ++qg) sc[qg] = (floatx4){-12.f, -12.f, -12.f, -12.f};
        __builtin_amdgcn_s_setprio(1);
        #pragma unroll
        for (int qg = 0; qg < 4; ++qg) {
            sc[qg] = __builtin_amdgcn_mfma_f32_16x16x32_bf16(kf0, qf[qg][0], sc[qg], 0, 0, 0);
            sc[qg] = __builtin_amdgcn_mfma_f32_16x16x32_bf16(kf1, qf[qg][1], sc[qg], 0, 0, 0);
        }

        // V fragments from buf[cur] (A-layout for 16x16x16: row=16nd+q16)
        const unsigned short* vbase = Vs + cur * 4096;
        half4v vf[4];
        #pragma unroll
        for (int nd = 0; nd < 4; ++nd)
            vf[nd] = *(const half4v*)&vbase[vroff + nd * 1024];

        // p = exp2(sc); pack in-register into the PV B-fragment (k=quad*4+j)
        #pragma unroll
        for (int qg = 0; qg < 4; ++qg) {
            float p0 = __builtin_amdgcn_exp2f(sc[qg][0]);
            float p1 = __builtin_amdgcn_exp2f(sc[qg][1]);
            float p2 = __builtin_amdgcn_exp2f(sc[qg][2]);
            float p3 = __builtin_amdgcn_exp2f(sc[qg][3]);
            union { half4v h; fp16x2 f2[2]; } pf;
            pf.f2[0] = __builtin_amdgcn_cvt_pkrtz(p0, p1);
            pf.f2[1] = __builtin_amdgcn_cvt_pkrtz(p2, p3);
            acc_l[qg] = __builtin_amdgcn_mfma_f32_16x16x16f16(ones.h, pf.h, acc_l[qg], 0, 0, 0);
            #pragma unroll
            for (int nd = 0; nd < 4; ++nd)
                acc_o[nd][qg] = __builtin_amdgcn_mfma_f32_16x16x16f16(
                    vf[nd], pf.h, acc_o[nd][qg], 0, 0, 0);
        }
        __builtin_amdgcn_s_setprio(0);

        // publish buf^1 ds_writes + retire buf[cur] ds_reads; K/V global
        // prefetches stay in flight across the bare barrier
        asm volatile("s_waitcnt lgkmcnt(0)" ::: "memory");
        BARE_BARRIER();
        cur ^= 1;
    }

    // ---- epilogue: cross-wave reduction of l then O (wave w owns qg = w)
    if (quad == 0) {
        #pragma unroll
        for (int qg = 0; qg < 4; ++qg) lbuf[w][qg][q16] = acc_l[qg][0];
    }
    __syncthreads();
    float linv = 1.f / (lbuf[0][w][q16] + lbuf[1][w][q16] + lbuf[2][w][q16] + lbuf[3][w][q16]);

    float* obuf = (float*)smem;
    float* myw = obuf + ((w * 4) * 64 + lane) * 4;   // + qg*256
    float* myr = obuf + (w * 64 + lane) * 4;         // + wsrc*1024
    unsigned short* og = o + ((size_t)(b * S_ + s0 + 16 * w + q16)) * H_ + h * HD_ + 4 * quad;

    #pragma unroll
    for (int nd = 0; nd < 4; ++nd) {
        __syncthreads();                              // obuf free
        #pragma unroll
        for (int qg = 0; qg < 4; ++qg)
            *(floatx4*)(myw + qg * 256) = acc_o[nd][qg];
        __syncthreads();
        floatx4 r0 = *(const floatx4*)(myr);
        floatx4 r1 = *(const floatx4*)(myr + 1024);
        floatx4 r2 = *(const floatx4*)(myr + 2048);
        floatx4 r3 = *(const floatx4*)(myr + 3072);
        floatx4 s = (r0 + r1) + (r2 + r3);
        uint2 pk;
        pk.x = pk_bf16(s[0] * linv, s[1] * linv);
        pk.y = pk_bf16(s[2] * linv, s[3] * linv);
        *(uint2*)(og + nd * 16) = pk;
    }
}

// ---------------------------------------------------------------------------
extern "C" void kernel_launch(void* const* d_in, const int* in_sizes, int n_in,
                              void* d_out, int out_size, void* d_ws, size_t ws_size,
                              hipStream_t stream)
{
    const float* x     = (const float*)d_in[0];
    const float* ada   = (const float*)d_in[1];
    const float* freqs = (const float*)d_in[2];
    const float* w_qkv = (const float*)d_in[3];
    const float* w_o   = (const float*)d_in[4];
    const float* ln_w  = (const float*)d_in[5];
    const float* mod_w = (const float*)d_in[6];
    const float* mod_b = (const float*)d_in[7];
    const float* qn_w  = (const float*)d_in[8];
    const float* kn_w  = (const float*)d_in[9];
    float* out = (float*)d_out;

    float* ws  = (float*)d_ws;
    float* mod = ws;                                    // 6144 f (pad to 8192)
    unsigned short* hb    = (unsigned short*)(mod + 8192);   // B*S*H bf16
    unsigned short* qb    = hb + (size_t)B_ * S_ * H_;
    unsigned short* kb    = qb + (size_t)B_ * S_ * H_;
    unsigned short* vtb   = kb + (size_t)B_ * S_ * H_;
    unsigned short* ob    = vtb + (size_t)B_ * S_ * H_;
    unsigned short* wqkvb = ob + (size_t)B_ * S_ * H_;
    unsigned short* wob   = wqkvb + (size_t)H3_ * H_;

    cast_bf16_kernel<<<H3_ * H_ / (8 * 256), 256, 0, stream>>>(w_qkv, wqkvb, H3_ * H_);
    cast_bf16_kernel<<<H_ * H_ / (8 * 256), 256, 0, stream>>>(w_o, wob, H_ * H_);
    mod_gemv_kernel<<<B_ * H3_ / 4, 256, 0, stream>>>(ada, mod_w, mod_b, mod);
    ln_mod_kernel<<<B_ * S_, 256, 0, stream>>>(x, ln_w, mod, hb);
    gemm_qkv_fused_kernel<<<dim3(H3_ / 128, B_ * S_ / 128), 256, 0, stream>>>(
        hb, wqkvb, freqs, qn_w, kn_w, qb, kb, vtb);
    attn_mfma_kernel<<<dim3(S_ / 64, B_ * NH_), 256, 0, stream>>>(qb, kb, vtb, ob);
    gemm_bt_bf16_kernel<<<dim3(H_ / 64, B_ * S_ / 128), 256, 0, stream>>>(
        ob, wob, out, B_ * S_, H_, H_, mod + 2 * H_, H3_, 11);
}

// Round 13
// 230.446 us; speedup vs baseline: 1.1045x; 1.0211x over previous
//
#include <hip/hip_runtime.h>
#include <hip/hip_bf16.h>
#include <hip/hip_fp16.h>
#include <math.h>

// Problem constants
#define B_ 2
#define S_ 2048
#define H_ 1024
#define A_ 1024
#define NH_ 16
#define HD_ 64
#define H3_ 3072
#define EPS_ 1e-5f

typedef __attribute__((ext_vector_type(8))) short short8;   // 8 bf16 in 4 VGPRs
typedef __attribute__((ext_vector_type(4))) float floatx4;  // MFMA accumulator
typedef __attribute__((ext_vector_type(4))) _Float16 half4v; // 4 f16 in 2 VGPRs
typedef __attribute__((ext_vector_type(8))) _Float16 half8v; // 8 f16 in 4 VGPRs
typedef __attribute__((ext_vector_type(2))) __fp16 fp16x2;   // cvt_pkrtz result type

__device__ inline unsigned short f2bf(float x) {
    union { float f; unsigned u; } v; v.f = x;
    unsigned r = v.u + 0x7fffu + ((v.u >> 16) & 1u);   // RNE
    return (unsigned short)(r >> 16);
}

// packed f32x2 -> bf16x2 (v_cvt_pk_bf16_f32 on gfx950)
__device__ inline unsigned pk_bf16(float a, float b) {
    union { __hip_bfloat162 h; unsigned u; } v;
    v.h = __float22bfloat162_rn(make_float2(a, b));
    return v.u;
}

// packed f32x2 -> f16x2 (RNE)
__device__ inline unsigned pk_f16(float a, float b) {
    union { __half2 h; unsigned u; } v;
    v.h = __float22half2_rn(make_float2(a, b));
    return v.u;
}

// async global->LDS, 16B per lane; LDS dst must be wave-uniform base + lane*16
__device__ inline void gld_lds16(const void* g, void* l) {
    __builtin_amdgcn_global_load_lds(
        (const __attribute__((address_space(1))) unsigned int*)g,
        (__attribute__((address_space(3))) unsigned int*)l, 16, 0, 0);
}

// BARE s_barrier everywhere (m141 lesson; verified R10/R11). Ordering is
// carried by the "memory"-clobbered inline waitcnts preceding each barrier.
#define BARE_BARRIER() __builtin_amdgcn_s_barrier()

// ---------------------------------------------------------------------------
// Kernel 0: fp32 -> bf16 cast (weights), 8 elems/thread
// ---------------------------------------------------------------------------
__global__ __launch_bounds__(256) void cast_bf16_kernel(
    const float* __restrict__ in, unsigned short* __restrict__ out, int n)
{
    int i = (blockIdx.x * 256 + threadIdx.x) * 8;
    if (i >= n) return;
    float4 a = *(const float4*)(in + i);
    float4 b = *(const float4*)(in + i + 4);
    uint4 o;
    o.x = pk_bf16(a.x, a.y);
    o.y = pk_bf16(a.z, a.w);
    o.z = pk_bf16(b.x, b.y);
    o.w = pk_bf16(b.z, b.w);
    *(uint4*)(out + i) = o;
}

// ---------------------------------------------------------------------------
// Kernel 1: mod = silu(ada_cond) @ mod_w^T + mod_b     [B, 3H]
// ---------------------------------------------------------------------------
__global__ __launch_bounds__(256) void mod_gemv_kernel(
    const float* __restrict__ ada, const float* __restrict__ mod_w,
    const float* __restrict__ mod_b, float* __restrict__ mod)
{
    int wid = threadIdx.x >> 6;
    int lane = threadIdx.x & 63;
    int idx = blockIdx.x * 4 + wid;       // 0 .. B*3H-1
    int b = idx / H3_;
    int j = idx % H3_;
    const float* ar = ada + (size_t)b * A_;
    const float* wr = mod_w + (size_t)j * A_;
    float acc = 0.f;
    for (int a = lane; a < A_; a += 64) {
        float av = ar[a];
        float sv = av / (1.f + __expf(-av));   // silu
        acc += sv * wr[a];
    }
    #pragma unroll
    for (int m = 1; m < 64; m <<= 1) acc += __shfl_xor(acc, m);
    if (lane == 0) mod[idx] = acc + mod_b[j];
}

// ---------------------------------------------------------------------------
// Kernel 2: h = layernorm(x)*ln_w * (scale+1) + shift -> bf16  [B,S,H]
// ---------------------------------------------------------------------------
__global__ __launch_bounds__(256) void ln_mod_kernel(
    const float* __restrict__ x, const float* __restrict__ ln_w,
    const float* __restrict__ mod, unsigned short* __restrict__ hout)
{
    int row = blockIdx.x;          // over B*S
    int b = row >> 11;             // row / 2048
    const float* xr = x + (size_t)row * H_;
    int t = threadIdx.x;
    float4 xv = *(const float4*)(xr + t * 4);
    float s1 = xv.x + xv.y + xv.z + xv.w;
    float s2 = xv.x*xv.x + xv.y*xv.y + xv.z*xv.z + xv.w*xv.w;
    #pragma unroll
    for (int m = 1; m < 64; m <<= 1) { s1 += __shfl_xor(s1, m); s2 += __shfl_xor(s2, m); }
    __shared__ float r1[4], r2[4];
    int wid = t >> 6, lane = t & 63;
    if (lane == 0) { r1[wid] = s1; r2[wid] = s2; }
    __syncthreads();
    s1 = r1[0] + r1[1] + r1[2] + r1[3];
    s2 = r2[0] + r2[1] + r2[2] + r2[3];
    float mean = s1 * (1.f / H_);
    float var  = s2 * (1.f / H_) - mean * mean;
    float rstd = rsqrtf(var + EPS_);
    const float* mrow = mod + (size_t)b * H3_;
    float4 wv = *(const float4*)(ln_w + t * 4);
    float4 sc = *(const float4*)(mrow + t * 4);
    float4 sh = *(const float4*)(mrow + H_ + t * 4);
    float4 hv;
    hv.x = (xv.x - mean) * rstd * wv.x * (sc.x + 1.f) + sh.x;
    hv.y = (xv.y - mean) * rstd * wv.y * (sc.y + 1.f) + sh.y;
    hv.z = (xv.z - mean) * rstd * wv.z * (sc.z + 1.f) + sh.z;
    hv.w = (xv.w - mean) * rstd * wv.w * (sc.w + 1.f) + sh.w;
    uint2 o;
    o.x = pk_bf16(hv.x, hv.y);
    o.y = pk_bf16(hv.z, hv.w);
    *(uint2*)(hout + (size_t)row * H_ + t * 4) = o;
}

// ---------------------------------------------------------------------------
// Kernel 3: QKV GEMM with FUSED qk-LN + RoPE epilogue.
// R12-verified: BK=64, 2 LDS buffers, counted vmcnt, bare barriers, setprio.
// ---------------------------------------------------------------------------
__global__ __launch_bounds__(256) void gemm_qkv_fused_kernel(
    const unsigned short* __restrict__ A, const unsigned short* __restrict__ Bm,
    const float* __restrict__ freqs, const float* __restrict__ qn_w,
    const float* __restrict__ kn_w, unsigned short* __restrict__ qout,
    unsigned short* __restrict__ kout, unsigned short* __restrict__ vtout)
{
    __shared__ unsigned short As[2][128 * 64];
    __shared__ unsigned short Bs[2][128 * 64];
    const int K = H_;
    const int NIT = K / 64;               // 16
    int t = threadIdx.x;
    int w = t >> 6, lane = t & 63;
    int q16 = lane & 15, quad = lane >> 4;
    int wm = w >> 1, wn = w & 1;
    int m0 = blockIdx.y * 128, n0 = blockIdx.x * 128;

    int srow = lane >> 3;
    int scol = ((lane & 7) ^ ((lane >> 3) & 7)) << 3;   // elements
    const unsigned short* ga = A + (size_t)(m0 + (w << 5) + srow) * K + scol;
    const unsigned short* gb = Bm + (size_t)(n0 + (w << 5) + srow) * K + scol;

    floatx4 acc[4][4];
    #pragma unroll
    for (int mt = 0; mt < 4; ++mt)
        #pragma unroll
        for (int nt = 0; nt < 4; ++nt)
            acc[mt][nt] = (floatx4){0.f, 0.f, 0.f, 0.f};

    int arow = (wm * 64 + q16) * 64;
    int brow = (wn * 64 + q16) * 64;
    int sw0 = ((quad ^ (q16 & 7)) << 3);          // ks=0: c=quad
    int sw1 = (((4 + quad) ^ (q16 & 7)) << 3);    // ks=1: c=4+quad

    #pragma unroll
    for (int p = 0; p < 2; ++p) {
        #pragma unroll
        for (int j = 0; j < 4; ++j) {
            gld_lds16(ga + p * 64 + (size_t)(j * 8) * K, &As[p][(w * 32 + j * 8) * 64]);
            gld_lds16(gb + p * 64 + (size_t)(j * 8) * K, &Bs[p][(w * 32 + j * 8) * 64]);
        }
    }

    for (int kt = 0; kt < NIT; ++kt) {
        int cb = kt & 1;
        if (kt < NIT - 1) asm volatile("s_waitcnt vmcnt(8)" ::: "memory");
        else              asm volatile("s_waitcnt vmcnt(0)" ::: "memory");
        BARE_BARRIER();                   // B1: tile kt resident in LDS

        const unsigned short* curA = &As[cb][0];
        const unsigned short* curB = &Bs[cb][0];

        __builtin_amdgcn_s_setprio(1);
        #pragma unroll
        for (int ks = 0; ks < 2; ++ks) {
            int sw = ks ? sw1 : sw0;
            short8 af[4], bf[4];
            #pragma unroll
            for (int mt = 0; mt < 4; ++mt)
                af[mt] = *(const short8*)&curA[arow + mt * 1024 + sw];
            #pragma unroll
            for (int nt = 0; nt < 4; ++nt)
                bf[nt] = *(const short8*)&curB[brow + nt * 1024 + sw];
            #pragma unroll
            for (int mt = 0; mt < 4; ++mt)
                #pragma unroll
                for (int nt = 0; nt < 4; ++nt)
                    acc[mt][nt] = __builtin_amdgcn_mfma_f32_16x16x32_bf16(
                        af[mt], bf[nt], acc[mt][nt], 0, 0, 0);
        }
        __builtin_amdgcn_s_setprio(0);

        asm volatile("s_waitcnt lgkmcnt(0)" ::: "memory");
        BARE_BARRIER();                   // B2: all reads of buf cb complete

        if (kt + 2 < NIT) {
            const unsigned short* ga2 = ga + (kt + 2) * 64;
            const unsigned short* gb2 = gb + (kt + 2) * 64;
            #pragma unroll
            for (int j = 0; j < 4; ++j) {
                gld_lds16(ga2 + (size_t)(j * 8) * K, &As[cb][(w * 32 + j * 8) * 64]);
                gld_lds16(gb2 + (size_t)(j * 8) * K, &Bs[cb][(w * 32 + j * 8) * 64]);
            }
        }
    }

    int n_base = n0 + wn * 64;          // wave-uniform, 64-aligned
    int sec = n_base >> 10;             // 0=Q, 1=K, 2=V
    int head = (n_base & 1023) >> 6;    // 0..15

    if (sec == 2) {
        // V: vt[(b*16+head)*64 + d][s] (FP16), 4 consecutive s packed per store
        #pragma unroll
        for (int mt = 0; mt < 4; ++mt) {
            int m = m0 + wm * 64 + mt * 16 + quad * 4;
            int b = m >> 11, s = m & (S_ - 1);
            #pragma unroll
            for (int nt = 0; nt < 4; ++nt) {
                int d = nt * 16 + q16;
                unsigned short* dst =
                    vtout + ((size_t)((b * 16 + head) * 64 + d)) * S_ + s;
                uint2 pk;
                pk.x = pk_f16(acc[mt][nt][0], acc[mt][nt][1]);
                pk.y = pk_f16(acc[mt][nt][2], acc[mt][nt][3]);
                *(uint2*)dst = pk;
            }
        }
    } else {
        const float* nw = (sec == 0) ? qn_w : kn_w;
        float w4[4];
        #pragma unroll
        for (int nt = 0; nt < 4; ++nt) w4[nt] = nw[nt * 16 + q16];
        unsigned short* outp = (sec == 0) ? qout : kout;
        float qscale = (sec == 0) ? 0.1803368801111244f : 1.0f;  // (1/8)*log2e

        #pragma unroll
        for (int mt = 0; mt < 4; ++mt) {
            #pragma unroll
            for (int i = 0; i < 4; ++i) {
                int m = m0 + wm * 64 + mt * 16 + quad * 4 + i;
                int b = m >> 11, s = m & (S_ - 1);
                float v0 = acc[mt][0][i], v1 = acc[mt][1][i];
                float v2 = acc[mt][2][i], v3 = acc[mt][3][i];
                float s1 = (v0 + v1) + (v2 + v3);
                float s2 = (v0 * v0 + v1 * v1) + (v2 * v2 + v3 * v3);
                #pragma unroll
                for (int msk = 1; msk < 16; msk <<= 1) {
                    s1 += __shfl_xor(s1, msk);
                    s2 += __shfl_xor(s2, msk);
                }
                float mean = s1 * (1.f / 64);
                float var  = s2 * (1.f / 64) - mean * mean;
                float rstd = rsqrtf(var + EPS_);
                float vv[4];
                vv[0] = (v0 - mean) * rstd * w4[0];
                vv[1] = (v1 - mean) * rstd * w4[1];
                vv[2] = (v2 - mean) * rstd * w4[2];
                vv[3] = (v3 - mean) * rstd * w4[3];
                const float* fr = freqs + (size_t)s * 64;
                unsigned short* orow = outp + ((size_t)((b * 16 + head) * S_ + s)) * 64;
                #pragma unroll
                for (int nt = 0; nt < 4; ++nt) {
                    int c = nt * 16 + q16;
                    float vp = __shfl_xor(vv[nt], 1);
                    float2 ff = *(const float2*)(fr + (c & ~1));
                    float r = (c & 1) ? (vv[nt] * ff.x + vp * ff.y)
                                      : (vv[nt] * ff.x - vp * ff.y);
                    orow[c] = f2bf(r * qscale);
                }
            }
        }
    }
}

// ---------------------------------------------------------------------------
// Kernel 6: bf16 MFMA GEMM  C[M,N] = A[M,K] @ B[N,K]^T, fp32 out with
// per-(batch,col) gate. R12-verified: 128x64 tiles, BK=64, 2 LDS buffers,
// counted vmcnt, bare barriers, setprio.
// ---------------------------------------------------------------------------
__global__ __launch_bounds__(256) void gemm_bt_bf16_kernel(
    const unsigned short* __restrict__ A, const unsigned short* __restrict__ Bm,
    float* __restrict__ C, int M, int N, int K,
    const float* __restrict__ gate, int gate_stride, int batch_shift)
{
    __shared__ unsigned short As[2][128 * 64];
    __shared__ unsigned short Bs[2][64 * 64];
    const int NIT = 1024 / 64;            // K = 1024 -> 16
    int t = threadIdx.x;
    int w = t >> 6, lane = t & 63;
    int q16 = lane & 15, quad = lane >> 4;
    int m0 = blockIdx.y * 128, n0 = blockIdx.x * 64;

    int srow = lane >> 3;
    int scol = ((lane & 7) ^ ((lane >> 3) & 7)) << 3;
    const unsigned short* ga = A + (size_t)(m0 + (w << 5) + srow) * K + scol;
    const unsigned short* gb = Bm + (size_t)(n0 + (w << 4) + srow) * K + scol;

    floatx4 acc[2][4];
    #pragma unroll
    for (int mt = 0; mt < 2; ++mt)
        #pragma unroll
        for (int nt = 0; nt < 4; ++nt)
            acc[mt][nt] = (floatx4){0.f, 0.f, 0.f, 0.f};

    int arow = (w * 32 + q16) * 64;
    int brow = q16 * 64;
    int sw0 = ((quad ^ (q16 & 7)) << 3);
    int sw1 = (((4 + quad) ^ (q16 & 7)) << 3);

    #pragma unroll
    for (int p = 0; p < 2; ++p) {
        #pragma unroll
        for (int j = 0; j < 4; ++j)
            gld_lds16(ga + p * 64 + (size_t)(j * 8) * K, &As[p][(w * 32 + j * 8) * 64]);
        #pragma unroll
        for (int j = 0; j < 2; ++j)
            gld_lds16(gb + p * 64 + (size_t)(j * 8) * K, &Bs[p][(w * 16 + j * 8) * 64]);
    }

    for (int kt = 0; kt < NIT; ++kt) {
        int cb = kt & 1;
        if (kt < NIT - 1) asm volatile("s_waitcnt vmcnt(6)" ::: "memory");
        else              asm volatile("s_waitcnt vmcnt(0)" ::: "memory");
        BARE_BARRIER();                   // B1: tile kt resident

        const unsigned short* curA = &As[cb][0];
        const unsigned short* curB = &Bs[cb][0];

        __builtin_amdgcn_s_setprio(1);
        #pragma unroll
        for (int ks = 0; ks < 2; ++ks) {
            int sw = ks ? sw1 : sw0;
            short8 af[2], bf[4];
            #pragma unroll
            for (int mt = 0; mt < 2; ++mt)
                af[mt] = *(const short8*)&curA[arow + mt * 1024 + sw];
            #pragma unroll
            for (int nt = 0; nt < 4; ++nt)
                bf[nt] = *(const short8*)&curB[brow + nt * 1024 + sw];
            #pragma unroll
            for (int mt = 0; mt < 2; ++mt)
                #pragma unroll
                for (int nt = 0; nt < 4; ++nt)
                    acc[mt][nt] = __builtin_amdgcn_mfma_f32_16x16x32_bf16(
                        af[mt], bf[nt], acc[mt][nt], 0, 0, 0);
        }
        __builtin_amdgcn_s_setprio(0);

        asm volatile("s_waitcnt lgkmcnt(0)" ::: "memory");
        BARE_BARRIER();                   // B2: reads of buf cb complete

        if (kt + 2 < NIT) {
            const unsigned short* ga2 = ga + (kt + 2) * 64;
            const unsigned short* gb2 = gb + (kt + 2) * 64;
            #pragma unroll
            for (int j = 0; j < 4; ++j)
                gld_lds16(ga2 + (size_t)(j * 8) * K, &As[cb][(w * 32 + j * 8) * 64]);
            #pragma unroll
            for (int j = 0; j < 2; ++j)
                gld_lds16(gb2 + (size_t)(j * 8) * K, &Bs[cb][(w * 16 + j * 8) * 64]);
        }
    }

    #pragma unroll
    for (int mt = 0; mt < 2; ++mt) {
        #pragma unroll
        for (int i = 0; i < 4; ++i) {
            int m = m0 + w * 32 + mt * 16 + quad * 4 + i;
            float* crow = C + (size_t)m * N;
            const float* grow = gate ? gate + (size_t)(m >> batch_shift) * gate_stride
                                     : nullptr;
            #pragma unroll
            for (int nt = 0; nt < 4; ++nt) {
                int n = n0 + nt * 16 + q16;
                float v = acc[mt][nt][i];
                if (gate) v *= grow[n];
                crow[n] = v;
            }
        }
    }
}

// ---------------------------------------------------------------------------
// Kernel 5: bf16/f16-MFMA flash attention, STATIC-shift softmax.
// Round-20: TWO-TILE PAIRING -> PV uses 16x16x32 f16 (K=32), halving PV's
// MFMA issue cycles (K=16 shapes deliver half FLOP per issue slot).
// Per iteration (2 tiles = 128 keys): wave holds P for 32 keys (two QK
// C-tiles); B-fragment k=quad*8+j maps j<4 -> tileA key quad*4+j, j>=4 ->
// tileB (same mapping on the V A-operand: concat of the two 8B swizzled
// tile reads). Barriers halve (16 iters). Key-split + dbuf-V-pairs,
// bare barriers, setprio; K/V prefetches survive barriers.
// ---------------------------------------------------------------------------
__global__ __launch_bounds__(256, 2) void attn_mfma_kernel(
    const unsigned short* __restrict__ q, const unsigned short* __restrict__ k,
    const unsigned short* __restrict__ vt, unsigned short* __restrict__ o)
{
    __shared__ __align__(16) unsigned char smem[32 * 1024]; // Vs[2 pairs][2 tiles][8KB]; obuf aliases
    __shared__ float lbuf[4][4][16];
    unsigned short* Vs = (unsigned short*)smem;   // swizzled [64 d][64 k] f16 per tile

    int t = threadIdx.x;
    int w = t >> 6, lane = t & 63;
    int q16 = lane & 15, quad = lane >> 4;
    int bh = blockIdx.y, b = bh >> 4, h = bh & 15;
    int s0 = blockIdx.x * 64;

    // ---- Q fragments: all 64 queries, B-operand layout (row=q16, k=quad*8+j)
    const unsigned short* qgp = q + ((size_t)bh * S_ + s0) * HD_;
    short8 qf[4][2];
    #pragma unroll
    for (int qg = 0; qg < 4; ++qg)
        #pragma unroll
        for (int hh = 0; hh < 2; ++hh)
            qf[qg][hh] = *(const short8*)(qgp + (16 * qg + q16) * HD_ + hh * 32 + quad * 8);

    // ---- K fragment source: wave w owns keys 16w..16w+15 of each tile
    const unsigned short* kg = k + (size_t)bh * S_ * HD_ + (16 * w + q16) * HD_ + quad * 8;

    // ---- V staging: wave w stages d-rows [16w,16w+16) per tile
    const unsigned short* vg0 = vt + (size_t)bh * 64 * S_
                              + (size_t)(16 * w + (lane >> 3)) * S_ + (lane & 7) * 8;
    const unsigned short* vg1 = vg0 + 8 * S_;
    int vwoff0 = (16 * w + (lane >> 3)) * 64 + (((lane & 7) ^ (lane >> 3)) << 3);
    int vwoff1 = vwoff0 + 512;
    // swizzled read offset: row=q16 (+16nd), keys 16w+4quad..+3 (8B)
    int vroff = q16 * 64 + (((2 * w + (quad >> 1)) ^ (q16 & 7)) << 3) + ((quad & 1) << 2);

    const int NP = S_ / 128;              // 16 pairs

    // prologue: K(pair0) + V(pair0) in flight
    short8 kfa0n = *(const short8*)kg;
    short8 kfa1n = *(const short8*)(kg + 32);
    short8 kfb0n = *(const short8*)(kg + 4096);
    short8 kfb1n = *(const short8*)(kg + 4096 + 32);
    uint4 vra0 = *(const uint4*)vg0;
    uint4 vra1 = *(const uint4*)vg1;
    uint4 vrb0 = *(const uint4*)(vg0 + 64);
    uint4 vrb1 = *(const uint4*)(vg1 + 64);
    vg0 += 128; vg1 += 128;

    // write pair0 -> buf0 (waits on vr), then issue V(pair1) loads
    *(uint4*)(Vs + vwoff0) = vra0;
    *(uint4*)(Vs + vwoff1) = vra1;
    *(uint4*)(Vs + 4096 + vwoff0) = vrb0;
    *(uint4*)(Vs + 4096 + vwoff1) = vrb1;
    vra0 = *(const uint4*)vg0;
    vra1 = *(const uint4*)vg1;
    vrb0 = *(const uint4*)(vg0 + 64);
    vrb1 = *(const uint4*)(vg1 + 64);
    vg0 += 128; vg1 += 128;
    asm volatile("s_waitcnt lgkmcnt(0)" ::: "memory");
    BARE_BARRIER();                       // buf0 ready (pair1 loads in flight)

    // f16 ones A-fragment (8 halves) for the l-row K=32 MFMA
    union { half8v h; unsigned u[4]; } ones;
    ones.u[0] = 0x3C003C00u; ones.u[1] = 0x3C003C00u;
    ones.u[2] = 0x3C003C00u; ones.u[3] = 0x3C003C00u;

    floatx4 acc_o[4][4];   // [nd][qg]: O^T[d=16nd+4quad+i][q=16qg+q16] partial
    floatx4 acc_l[4];      // [qg]: row sums of P (all rows identical)
    #pragma unroll
    for (int nd = 0; nd < 4; ++nd)
        #pragma unroll
        for (int qg = 0; qg < 4; ++qg)
            acc_o[nd][qg] = (floatx4){0.f, 0.f, 0.f, 0.f};
    #pragma unroll
    for (int qg = 0; qg < 4; ++qg) acc_l[qg] = (floatx4){0.f, 0.f, 0.f, 0.f};

    for (int i = 0; i < NP; ++i) {
        int cur = i & 1;
        short8 kfa0 = kfa0n, kfa1 = kfa1n;   // waits on prefetched K(pair i)
        short8 kfb0 = kfb0n, kfb1 = kfb1n;

        if (i + 1 < NP) {
            // write V(pair i+1) -> buf^1 (waits on vr); prev barrier protects it
            unsigned short* wb = Vs + (cur ^ 1) * 8192;
            *(uint4*)(wb + vwoff0) = vra0;
            *(uint4*)(wb + vwoff1) = vra1;
            *(uint4*)(wb + 4096 + vwoff0) = vrb0;
            *(uint4*)(wb + 4096 + vwoff1) = vrb1;
            // issue K(pair i+1) and V(pair i+2) loads; fly across the barrier
            kg += 128 * HD_;
            kfa0n = *(const short8*)kg;
            kfa1n = *(const short8*)(kg + 32);
            kfb0n = *(const short8*)(kg + 4096);
            kfb1n = *(const short8*)(kg + 4096 + 32);
            if (i + 2 < NP) {
                vra0 = *(const uint4*)vg0;
                vra1 = *(const uint4*)vg1;
                vrb0 = *(const uint4*)(vg0 + 64);
                vrb1 = *(const uint4*)(vg1 + 64);
                vg0 += 128; vg1 += 128;
            }
        }

        // QK^T for both tiles: S^T[key=quad*4+i][q=16qg+q16]; C-init = -12
        floatx4 sa[4], sb[4];
        #pragma unroll
        for (int qg = 0; qg < 4; ++qg) {
            sa[qg] = (floatx4){-12.f, -12.f, -12.f, -12.f};
            sb[qg] = (floatx4){-12.f, -12.f, -12.f, -12.f};
        }
        __builtin_amdgcn_s_setprio(1);
        #pragma unroll
        for (int qg = 0; qg < 4; ++qg) {
            sa[qg] = __builtin_amdgcn_mfma_f32_16x16x32_bf16(kfa0, qf[qg][0], sa[qg], 0, 0, 0);
            sa[qg] = __builtin_amdgcn_mfma_f32_16x16x32_bf16(kfa1, qf[qg][1], sa[qg], 0, 0, 0);
            sb[qg] = __builtin_amdgcn_mfma_f32_16x16x32_bf16(kfb0, qf[qg][0], sb[qg], 0, 0, 0);
            sb[qg] = __builtin_amdgcn_mfma_f32_16x16x32_bf16(kfb1, qf[qg][1], sb[qg], 0, 0, 0);
        }

        // V fragments: concat tileA/tileB 8B swizzled reads -> K=32 A-operand
        const unsigned short* va = Vs + cur * 8192;
        const unsigned short* vb = va + 4096;
        half8v vf[4];
        #pragma unroll
        for (int nd = 0; nd < 4; ++nd) {
            union { half8v v8; half4v v4[2]; } u;
            u.v4[0] = *(const half4v*)&va[vroff + nd * 1024];
            u.v4[1] = *(const half4v*)&vb[vroff + nd * 1024];
            vf[nd] = u.v8;
        }

        // p = exp2(s); pack both tiles into the K=32 PV B-fragment
        #pragma unroll
        for (int qg = 0; qg < 4; ++qg) {
            float a0 = __builtin_amdgcn_exp2f(sa[qg][0]);
            float a1 = __builtin_amdgcn_exp2f(sa[qg][1]);
            float a2 = __builtin_amdgcn_exp2f(sa[qg][2]);
            float a3 = __builtin_amdgcn_exp2f(sa[qg][3]);
            float b0 = __builtin_amdgcn_exp2f(sb[qg][0]);
            float b1 = __builtin_amdgcn_exp2f(sb[qg][1]);
            float b2 = __builtin_amdgcn_exp2f(sb[qg][2]);
            float b3 = __builtin_amdgcn_exp2f(sb[qg][3]);
            union { half8v h; fp16x2 f2[4]; } pf;
            pf.f2[0] = __builtin_amdgcn_cvt_pkrtz(a0, a1);
            pf.f2[1] = __builtin_amdgcn_cvt_pkrtz(a2, a3);
            pf.f2[2] = __builtin_amdgcn_cvt_pkrtz(b0, b1);
            pf.f2[3] = __builtin_amdgcn_cvt_pkrtz(b2, b3);
            acc_l[qg] = __builtin_amdgcn_mfma_f32_16x16x32_f16(ones.h, pf.h, acc_l[qg], 0, 0, 0);
            #pragma unroll
            for (int nd = 0; nd < 4; ++nd)
                acc_o[nd][qg] = __builtin_amdgcn_mfma_f32_16x16x32_f16(
                    vf[nd], pf.h, acc_o[nd][qg], 0, 0, 0);
        }
        __builtin_amdgcn_s_setprio(0);

        // publish buf^1 ds_writes + retire buf[cur] ds_reads; global
        // prefetches stay in flight across the bare barrier
        asm volatile("s_waitcnt lgkmcnt(0)" ::: "memory");
        BARE_BARRIER();
    }

    // ---- epilogue: cross-wave reduction of l then O (wave w owns qg = w)
    if (quad == 0) {
        #pragma unroll
        for (int qg = 0; qg < 4; ++qg) lbuf[w][qg][q16] = acc_l[qg][0];
    }
    __syncthreads();
    float linv = 1.f / (lbuf[0][w][q16] + lbuf[1][w][q16] + lbuf[2][w][q16] + lbuf[3][w][q16]);

    float* obuf = (float*)smem;
    float* myw = obuf + ((w * 4) * 64 + lane) * 4;   // + qg*256
    float* myr = obuf + (w * 64 + lane) * 4;         // + wsrc*1024
    unsigned short* og = o + ((size_t)(b * S_ + s0 + 16 * w + q16)) * H_ + h * HD_ + 4 * quad;

    #pragma unroll
    for (int nd = 0; nd < 4; ++nd) {
        __syncthreads();                              // obuf free
        #pragma unroll
        for (int qg = 0; qg < 4; ++qg)
            *(floatx4*)(myw + qg * 256) = acc_o[nd][qg];
        __syncthreads();
        floatx4 r0 = *(const floatx4*)(myr);
        floatx4 r1 = *(const floatx4*)(myr + 1024);
        floatx4 r2 = *(const floatx4*)(myr + 2048);
        floatx4 r3 = *(const floatx4*)(myr + 3072);
        floatx4 s = (r0 + r1) + (r2 + r3);
        uint2 pk;
        pk.x = pk_bf16(s[0] * linv, s[1] * linv);
        pk.y = pk_bf16(s[2] * linv, s[3] * linv);
        *(uint2*)(og + nd * 16) = pk;
    }
}

// ---------------------------------------------------------------------------
extern "C" void kernel_launch(void* const* d_in, const int* in_sizes, int n_in,
                              void* d_out, int out_size, void* d_ws, size_t ws_size,
                              hipStream_t stream)
{
    const float* x     = (const float*)d_in[0];
    const float* ada   = (const float*)d_in[1];
    const float* freqs = (const float*)d_in[2];
    const float* w_qkv = (const float*)d_in[3];
    const float* w_o   = (const float*)d_in[4];
    const float* ln_w  = (const float*)d_in[5];
    const float* mod_w = (const float*)d_in[6];
    const float* mod_b = (const float*)d_in[7];
    const float* qn_w  = (const float*)d_in[8];
    const float* kn_w  = (const float*)d_in[9];
    float* out = (float*)d_out;

    float* ws  = (float*)d_ws;
    float* mod = ws;                                    // 6144 f (pad to 8192)
    unsigned short* hb    = (unsigned short*)(mod + 8192);   // B*S*H bf16
    unsigned short* qb    = hb + (size_t)B_ * S_ * H_;
    unsigned short* kb    = qb + (size_t)B_ * S_ * H_;
    unsigned short* vtb   = kb + (size_t)B_ * S_ * H_;
    unsigned short* ob    = vtb + (size_t)B_ * S_ * H_;
    unsigned short* wqkvb = ob + (size_t)B_ * S_ * H_;
    unsigned short* wob   = wqkvb + (size_t)H3_ * H_;

    cast_bf16_kernel<<<H3_ * H_ / (8 * 256), 256, 0, stream>>>(w_qkv, wqkvb, H3_ * H_);
    cast_bf16_kernel<<<H_ * H_ / (8 * 256), 256, 0, stream>>>(w_o, wob, H_ * H_);
    mod_gemv_kernel<<<B_ * H3_ / 4, 256, 0, stream>>>(ada, mod_w, mod_b, mod);
    ln_mod_kernel<<<B_ * S_, 256, 0, stream>>>(x, ln_w, mod, hb);
    gemm_qkv_fused_kernel<<<dim3(H3_ / 128, B_ * S_ / 128), 256, 0, stream>>>(
        hb, wqkvb, freqs, qn_w, kn_w, qb, kb, vtb);
    attn_mfma_kernel<<<dim3(S_ / 64, B_ * NH_), 256, 0, stream>>>(qb, kb, vtb, ob);
    gemm_bt_bf16_kernel<<<dim3(H_ / 64, B_ * S_ / 128), 256, 0, stream>>>(
        ob, wob, out, B_ * S_, H_, H_, mod + 2 * H_, H3_, 11);
}